// Round 4
// baseline (181.517 us; speedup 1.0000x reference)
//
#include <hip/hip_runtime.h>
#include <hip/hip_bf16.h>
#include <cmath>

#define DDIM 128
#define NPTS 3136   // 56*56
#define NCHUNK 196  // NPTS/16
#define BATCH 16
#define PROT 2000
#define PPAD 2048   // 16 tiles * 128

typedef __attribute__((ext_vector_type(8))) short bf16x8;
typedef __attribute__((ext_vector_type(4))) float f32x4;
typedef __attribute__((ext_vector_type(4))) unsigned int u32x4;

// ---- workspace layout (float indices) ----
#define WS_X2   0                      // 50176
#define WS_N1   50176                  // 32768
#define WS_N2   82944                  // 32768
#define WS_PT   115712                 // 262144 (= 524288 shorts, 2048x256)
#define WS_XT   377856                 // 6422528 (= 16*196*8192 bytes)
#define WS_XFT  6800384                // 6422528 (16*3136*128 f32)
#define WS_MID  ((size_t)6800384 * 4)
#define WS_BIG  ((size_t)13222912 * 4)

// ---------------- bf16 split helpers ----------------
__device__ inline unsigned short bf16rn(float a) {
    unsigned u = __float_as_uint(a);
    unsigned r = u + 0x7FFFu + ((u >> 16) & 1u);
    return (unsigned short)(r >> 16);
}
__device__ inline void split2(float a, unsigned short& h, unsigned short& l) {
    h = bf16rn(a);
    float hf = __uint_as_float(((unsigned)h) << 16);
    l = bf16rn(a - hf);
}

__device__ __forceinline__ void gload_lds16(const void* g, void* l) {
    __builtin_amdgcn_global_load_lds(
        (const __attribute__((address_space(1))) void*)g,
        (__attribute__((address_space(3))) void*)l, 16, 0, 0);
}

// ---------------- prototype pre-pass: pt[p][kk][hi/lo][32] ----------------
__global__ void pp_p(const float* __restrict__ proto, unsigned short* __restrict__ pt) {
    int p = blockIdx.x * blockDim.x + threadIdx.x; // 0..2047
    if (p >= PPAD) return;
    int ps = min(p, PROT - 1);
    const float* src = proto + (size_t)ps * DDIM;
    unsigned short* dst = pt + (size_t)p * 256;
    for (int kk = 0; kk < 4; ++kk) {
        for (int j = 0; j < 32; ++j) {
            unsigned short h, l;
            split2(src[kk * 32 + j], h, l);
            dst[kk * 64 + j] = h;
            dst[kk * 64 + 32 + j] = l;
        }
    }
}

// ---------------- x pre-pass ----------------
// Emits: xt  = bf16-split A chunks, chunk-major [b][ci][8KB], XOR-swizzled
//        x2  = per-point |x|^2
//        xfT = transposed fp32 features [b][n][d] (optional)
__global__ __launch_bounds__(256)
void pp_x(const float* __restrict__ x, unsigned short* __restrict__ xt,
          float* __restrict__ x2, float* __restrict__ xfT) {
    __shared__ float xs[DDIM][64];
    int b = blockIdx.y;
    int n0 = blockIdx.x * 64;
    int tid = threadIdx.x;
    {
        int r = tid >> 4, c = tid & 15;
        #pragma unroll
        for (int it = 0; it < 8; ++it) {
            int row = it * 16 + r;
            f32x4 v = *(const f32x4*)(x + ((size_t)(b * DDIM + row)) * NPTS + n0 + c * 4);
            *(f32x4*)(&xs[row][c * 4]) = v;
        }
    }
    __syncthreads();
    if (tid < 64) {
        float s = 0.f;
        #pragma unroll 8
        for (int d = 0; d < DDIM; ++d) { float v = xs[d][tid]; s = fmaf(v, v, s); }
        x2[b * NPTS + n0 + tid] = s;
    }
    int n = tid & 63, kk = tid >> 6;
    int nl = n & 15, ci = (n0 + n) >> 4;
    unsigned int hw[16], lw[16];
    #pragma unroll
    for (int j = 0; j < 16; ++j) {
        unsigned short h0, l0, h1, l1;
        split2(xs[kk * 32 + 2 * j][n], h0, l0);
        split2(xs[kk * 32 + 2 * j + 1][n], h1, l1);
        hw[j] = (unsigned)h0 | ((unsigned)h1 << 16);
        lw[j] = (unsigned)l0 | ((unsigned)l1 << 16);
    }
    char* cb = (char*)xt + ((size_t)b * NCHUNK + ci) * 8192;
    int swz = (nl & 7) << 4;
    #pragma unroll
    for (int q = 0; q < 4; ++q) {
        int ohi = nl * 512 + kk * 128 + q * 16;
        *(u32x4*)(cb + (ohi ^ swz)) = *(u32x4*)(&hw[q * 4]);
        *(u32x4*)(cb + ((ohi + 64) ^ swz)) = *(u32x4*)(&lw[q * 4]);
    }
    if (xfT) {
        float* fo = xfT + ((size_t)b * NPTS + n0 + n) * DDIM + kk * 32;
        #pragma unroll 8
        for (int j = 0; j < 32; ++j) fo[j] = xs[kk * 32 + j][n];
    }
}

// ---------------- main MFMA kernel ----------------
// grid 256 (16 ptile x 16 b) XCD-swizzled; block 512 = 8 waves = (4 psg x 2 nq).
// p-tile = 128. B resident in regs (2 ps/wave); A chunks staged ONCE per chunk
// (each psg wave DMAs 2 KB of the 8 KB), double-buffered per nq stream.
__global__ __launch_bounds__(512, 4)
void proto_mfma(const unsigned short* __restrict__ xt,
                const unsigned short* __restrict__ pt,
                const float* __restrict__ x2,
                int* __restrict__ n1w, int* __restrict__ n2w) {
    __shared__ char As[2][2][8192];            // 32 KB [buf][nq]
    __shared__ float rb1[2][128], rb2[2][128]; // 2 KB
    __shared__ int   rn1[2][128], rn2[2][128]; // 2 KB

    int lid = blockIdx.x;                      // 0..255
    int sid = (lid & 7) * 32 + (lid >> 3);     // bijective XCD chunking (256%8==0)
    int b = sid >> 4;
    int pbase = (sid & 15) * 128;

    int tid = threadIdx.x;
    int lane = tid & 63, wave = tid >> 6;
    int psg = wave & 3, nq = wave >> 2;        // 4 p-groups x 2 n-streams
    int l15 = lane & 15, lg = lane >> 4;

    // B fragments: 2 ps x 4 kk x {hi,lo}, resident
    bf16x8 Bh[2][4], Bl[2][4];
    #pragma unroll
    for (int ps = 0; ps < 2; ++ps) {
        int p = pbase + psg * 32 + ps * 16 + l15;
        const unsigned short* bp = pt + (size_t)p * 256 + lg * 8;
        #pragma unroll
        for (int kk = 0; kk < 4; ++kk) {
            Bh[ps][kk] = *(const bf16x8*)(bp + kk * 64);
            Bl[ps][kk] = *(const bf16x8*)(bp + kk * 64 + 32);
        }
    }

    const char* srcBase = (const char*)xt + (size_t)b * NCHUNK * 8192;
    // swizzled per-lane LDS fragment base (matches pp_x writer layout)
    int preA = ((l15 << 9) | (lg << 4)) ^ ((l15 & 7) << 4);

    float b1[2], b2[2];
    int   i1[2], i2[2];
    #pragma unroll
    for (int ps = 0; ps < 2; ++ps) { b1[ps] = 3e38f; b2[ps] = 3e38f; i1[ps] = 0; i2[ps] = 0; }

    // prologue: stage chunk (c = nq) into buf 0; each psg wave stages 2 KB
    {
        const char* src = srcBase + (size_t)nq * 8192 + psg * 2048 + (size_t)lane * 16;
        gload_lds16(src,        &As[0][nq][psg * 2048]);
        gload_lds16(src + 1024, &As[0][nq][psg * 2048 + 1024]);
    }
    __syncthreads();

    #pragma unroll 1
    for (int t = 0; t < 98; ++t) {
        int cur = t & 1;
        int c = nq + 2 * t;
        if (t < 97) {
            const char* src = srcBase + ((size_t)c + 2) * 8192 + psg * 2048 + (size_t)lane * 16;
            gload_lds16(src,        &As[cur ^ 1][nq][psg * 2048]);
            gload_lds16(src + 1024, &As[cur ^ 1][nq][psg * 2048 + 1024]);
        }
        const char* ab = &As[cur][nq][0];
        float x2r[4];
        {
            const float* xp = x2 + b * NPTS + c * 16 + lg * 4;
            #pragma unroll
            for (int rr = 0; rr < 4; ++rr) x2r[rr] = xp[rr];
        }

        f32x4 acc[2];
        acc[0] = {0.f, 0.f, 0.f, 0.f};
        acc[1] = {0.f, 0.f, 0.f, 0.f};
        #pragma unroll
        for (int kk = 0; kk < 4; ++kk) {
            bf16x8 Ah = *(const bf16x8*)(ab + (preA ^ (kk * 128)));
            bf16x8 Al = *(const bf16x8*)(ab + (preA ^ (kk * 128 + 64)));
            acc[0] = __builtin_amdgcn_mfma_f32_16x16x32_bf16(Ah, Bh[0][kk], acc[0], 0, 0, 0);
            acc[1] = __builtin_amdgcn_mfma_f32_16x16x32_bf16(Ah, Bh[1][kk], acc[1], 0, 0, 0);
            acc[0] = __builtin_amdgcn_mfma_f32_16x16x32_bf16(Ah, Bl[0][kk], acc[0], 0, 0, 0);
            acc[1] = __builtin_amdgcn_mfma_f32_16x16x32_bf16(Ah, Bl[1][kk], acc[1], 0, 0, 0);
            acc[0] = __builtin_amdgcn_mfma_f32_16x16x32_bf16(Al, Bh[0][kk], acc[0], 0, 0, 0);
            acc[1] = __builtin_amdgcn_mfma_f32_16x16x32_bf16(Al, Bh[1][kk], acc[1], 0, 0, 0);
        }

        int nb = c * 16 + lg * 4;
        #pragma unroll
        for (int ps = 0; ps < 2; ++ps) {
            #pragma unroll
            for (int rr = 0; rr < 4; ++rr) {
                float v = fmaf(acc[ps][rr], -2.f, x2r[rr]);   // = d2 - p2[p]
                int n = nb + rr;
                bool c1 = v < b1[ps];
                bool c2 = v < b2[ps];
                i2[ps] = c1 ? i1[ps] : (c2 ? n : i2[ps]);
                b2[ps] = c1 ? b1[ps] : (c2 ? v : b2[ps]);
                i1[ps] = c1 ? n : i1[ps];
                b1[ps] = c1 ? v : b1[ps];
            }
        }
        __syncthreads();
    }

    // ---- reduce across the 4 row-groups (lanes l, l+16, l+32, l+48) ----
    #pragma unroll
    for (int m = 16; m <= 32; m <<= 1) {
        #pragma unroll
        for (int ps = 0; ps < 2; ++ps) {
            float c1v = __shfl_xor(b1[ps], m, 64);
            float c2v = __shfl_xor(b2[ps], m, 64);
            int   cn1 = __shfl_xor(i1[ps], m, 64);
            int   cn2 = __shfl_xor(i2[ps], m, 64);
            bool cl = (c1v < b1[ps]) || (c1v == b1[ps] && cn1 < i1[ps]);
            float m1 = cl ? c1v : b1[ps]; int mn1 = cl ? cn1 : i1[ps];
            float w1 = cl ? b1[ps] : c1v; int wn1 = cl ? i1[ps] : cn1;
            bool tt = (b2[ps] < c2v) || (b2[ps] == c2v && i2[ps] < cn2);
            float s2 = tt ? b2[ps] : c2v; int sn2 = tt ? i2[ps] : cn2;
            bool u = (w1 < s2) || (w1 == s2 && wn1 < sn2);
            b1[ps] = m1; i1[ps] = mn1;
            b2[ps] = u ? w1 : s2; i2[ps] = u ? wn1 : sn2;
        }
    }

    if (lg == 0) {
        #pragma unroll
        for (int ps = 0; ps < 2; ++ps) {
            int idx = psg * 32 + ps * 16 + l15;
            rb1[nq][idx] = b1[ps]; rb2[nq][idx] = b2[ps];
            rn1[nq][idx] = i1[ps]; rn2[nq][idx] = i2[ps];
        }
    }
    __syncthreads();
    if (tid < 128) {
        float B1 = rb1[0][tid], B2 = rb2[0][tid];
        int   N1 = rn1[0][tid], N2 = rn2[0][tid];
        {
            float c1v = rb1[1][tid], c2v = rb2[1][tid];
            int   cn1 = rn1[1][tid], cn2 = rn2[1][tid];
            bool cl = (c1v < B1) || (c1v == B1 && cn1 < N1);
            float m1 = cl ? c1v : B1; int mn1 = cl ? cn1 : N1;
            float w1 = cl ? B1 : c1v; int wn1 = cl ? N1 : cn1;
            bool tt = (B2 < c2v) || (B2 == c2v && N2 < cn2);
            float s2 = tt ? B2 : c2v; int sn2 = tt ? N2 : cn2;
            bool u = (w1 < s2) || (w1 == s2 && wn1 < sn2);
            B1 = m1; N1 = mn1;
            B2 = u ? w1 : s2; N2 = u ? wn1 : sn2;
        }
        n1w[(size_t)b * PPAD + pbase + tid] = N1;
        n2w[(size_t)b * PPAD + pbase + tid] = N2;
    }
}

// ---------------- exact fp32 fixup + all output writes ----------------
// MODE 0: coalesced via xfT; MODE 1: strided from x.
template<int MODE>
__global__ __launch_bounds__(256)
void fixup(const float* __restrict__ x, const float* __restrict__ xfT,
           const float* __restrict__ proto,
           const int* __restrict__ n1w, const int* __restrict__ n2w,
           float* __restrict__ out) {
    int tid = threadIdx.x;
    int lane = tid & 63, wv = tid >> 6;
    long long pair = (long long)blockIdx.x * 4 + wv;
    if (pair >= (long long)BATCH * PROT) return;
    int b = (int)(pair / PROT), p = (int)(pair % PROT);
    int n1 = n1w[(size_t)b * PPAD + p];
    int n2 = n2w[(size_t)b * PPAD + p];
    int d0 = lane, d1 = lane + 64;
    float xA0, xA1, xB0, xB1;
    if (MODE == 0) {
        const float* fA = xfT + ((size_t)b * NPTS + n1) * DDIM;
        const float* fB = xfT + ((size_t)b * NPTS + n2) * DDIM;
        xA0 = fA[d0]; xA1 = fA[d1];
        xB0 = fB[d0]; xB1 = fB[d1];
    } else {
        const float* xb = x + (size_t)b * DDIM * NPTS;
        xA0 = xb[(size_t)d0 * NPTS + n1]; xA1 = xb[(size_t)d1 * NPTS + n1];
        xB0 = xb[(size_t)d0 * NPTS + n2]; xB1 = xb[(size_t)d1 * NPTS + n2];
    }
    float pa0 = proto[(size_t)p * DDIM + d0], pa1 = proto[(size_t)p * DDIM + d1];
    float sxpA = xA0 * pa0 + xA1 * pa1;
    float sxpB = xB0 * pa0 + xB1 * pa1;
    float sx2A = xA0 * xA0 + xA1 * xA1;
    float sx2B = xB0 * xB0 + xB1 * xB1;
    float sp2  = pa0 * pa0 + pa1 * pa1;
    #pragma unroll
    for (int m = 1; m < 64; m <<= 1) {
        sxpA += __shfl_xor(sxpA, m, 64);
        sxpB += __shfl_xor(sxpB, m, 64);
        sx2A += __shfl_xor(sx2A, m, 64);
        sx2B += __shfl_xor(sx2B, m, 64);
        sp2  += __shfl_xor(sp2,  m, 64);
    }
    float d2A = fmaxf(sx2A + sp2 - 2.f * sxpA, 0.f);
    float d2B = fmaxf(sx2B + sp2 - 2.f * sxpB, 0.f);
    bool selB = (d2B < d2A) || (d2B == d2A && n2 < n1);
    float d2 = selB ? d2B : d2A;
    float dm = sqrtf(d2);
    float sim = logf((dm + 1.0f) / (dm + 1e-7f));
    if (lane == 0) {
        out[(size_t)b * PROT + p] = sim;
        out[(size_t)BATCH * PROT + (size_t)b * PROT + p] = dm;
    }
    float f0 = selB ? xB0 : xA0;
    float f1 = selB ? xB1 : xA1;
    float* fo = out + (size_t)2 * BATCH * PROT + ((size_t)b * PROT + p) * DDIM;
    fo[d0] = f0;
    fo[d1] = f1;
}

// ================= fallback fp32 path (round-1, known-good; dead in practice) ====
#define TP 64
#define TN 64
__global__ void p2_kernel(const float* __restrict__ proto, float* __restrict__ p2) {
    int p = blockIdx.x * blockDim.x + threadIdx.x;
    if (p >= PROT) return;
    const float4* pr = reinterpret_cast<const float4*>(proto + (size_t)p * DDIM);
    float s = 0.f;
    #pragma unroll
    for (int i = 0; i < DDIM / 4; ++i) {
        float4 v = pr[i];
        s += v.x * v.x + v.y * v.y + v.z * v.z + v.w * v.w;
    }
    p2[p] = s;
}
__global__ void x2_kernel(const float* __restrict__ x, float* __restrict__ x2) {
    int idx = blockIdx.x * blockDim.x + threadIdx.x;
    if (idx >= BATCH * NPTS) return;
    int b = idx / NPTS, n = idx - b * NPTS;
    const float* xp = x + (size_t)b * DDIM * NPTS + n;
    float s = 0.f;
    #pragma unroll 8
    for (int d = 0; d < DDIM; ++d) { float v = xp[(size_t)d * NPTS]; s += v * v; }
    x2[idx] = s;
}
__global__ __launch_bounds__(256, 2)
void proto_main(const float* __restrict__ x, const float* __restrict__ proto,
                const float* __restrict__ p2, const float* __restrict__ x2,
                float* __restrict__ out) {
    __shared__ __align__(16) float xs[DDIM][TN];
    __shared__ __align__(16) float pst[DDIM][TP];
    __shared__ float p2s[TP];
    __shared__ float x2s[TN];
    __shared__ float red_d2[16][TP];
    __shared__ int   red_n[16][TP];
    __shared__ int   bestn_s[TP];
    const int b = blockIdx.y;
    const int pbase = blockIdx.x * TP;
    const int tid = threadIdx.x;
    {
        #pragma unroll
        for (int it = 0; it < (TP * DDIM / 4) / 256; ++it) {
            int idx = it * 256 + tid;
            int p = idx / (DDIM / 4);
            int dq = idx - p * (DDIM / 4);
            int gp = min(pbase + p, PROT - 1);
            float4 v = reinterpret_cast<const float4*>(proto)[(size_t)gp * (DDIM / 4) + dq];
            pst[dq * 4 + 0][p] = v.x; pst[dq * 4 + 1][p] = v.y;
            pst[dq * 4 + 2][p] = v.z; pst[dq * 4 + 3][p] = v.w;
        }
        if (tid < TP) p2s[tid] = p2[min(pbase + tid, PROT - 1)];
    }
    const int tn = tid >> 4;
    const int tp = tid & 15;
    float best[4]; int bestn[4];
    #pragma unroll
    for (int j = 0; j < 4; ++j) { best[j] = 1e30f; bestn[j] = 0; }
    for (int n0 = 0; n0 < NPTS; n0 += TN) {
        __syncthreads();
        {
            int r = tid >> 4, c = tid & 15;
            #pragma unroll
            for (int it = 0; it < 8; ++it) {
                int row = it * 16 + r;
                float4 v = *reinterpret_cast<const float4*>(
                    x + ((size_t)(b * DDIM + row)) * NPTS + n0 + c * 4);
                *reinterpret_cast<float4*>(&xs[row][c * 4]) = v;
            }
        }
        if (tid < TN) x2s[tid] = x2[b * NPTS + n0 + tid];
        __syncthreads();
        float acc[4][4];
        #pragma unroll
        for (int i = 0; i < 4; ++i)
            #pragma unroll
            for (int j = 0; j < 4; ++j) acc[i][j] = 0.f;
        #pragma unroll 16
        for (int d = 0; d < DDIM; ++d) {
            const float4 a = *reinterpret_cast<const float4*>(&xs[d][tn * 4]);
            const float4 bv = *reinterpret_cast<const float4*>(&pst[d][tp * 4]);
            const float av[4] = {a.x, a.y, a.z, a.w};
            const float bw[4] = {bv.x, bv.y, bv.z, bv.w};
            #pragma unroll
            for (int i = 0; i < 4; ++i)
                #pragma unroll
                for (int j = 0; j < 4; ++j) acc[i][j] = fmaf(av[i], bw[j], acc[i][j]);
        }
        #pragma unroll
        for (int i = 0; i < 4; ++i) {
            float xv = x2s[tn * 4 + i];
            int n = n0 + tn * 4 + i;
            #pragma unroll
            for (int j = 0; j < 4; ++j) {
                float d2 = xv + p2s[tp * 4 + j] - 2.0f * acc[i][j];
                if (d2 < best[j]) { best[j] = d2; bestn[j] = n; }
            }
        }
    }
    #pragma unroll
    for (int j = 0; j < 4; ++j) {
        red_d2[tn][tp * 4 + j] = best[j];
        red_n[tn][tp * 4 + j] = bestn[j];
    }
    __syncthreads();
    if (tid < TP) {
        float bd = red_d2[0][tid]; int bn = red_n[0][tid];
        #pragma unroll
        for (int t = 1; t < 16; ++t) {
            float dv = red_d2[t][tid]; int nv = red_n[t][tid];
            if (dv < bd || (dv == bd && nv < bn)) { bd = dv; bn = nv; }
        }
        int gp = pbase + tid;
        if (gp < PROT) {
            float d2c = fmaxf(bd, 0.f);
            float dmin = sqrtf(d2c);
            float sim = logf((dmin + 1.0f) / (dmin + 1e-7f));
            out[(size_t)b * PROT + gp] = sim;
            out[(size_t)BATCH * PROT + (size_t)b * PROT + gp] = dmin;
        }
        bestn_s[tid] = bn;
    }
    __syncthreads();
    {
        int pl = tid >> 2, dbase = (tid & 3) * 32;
        int gp = pbase + pl;
        if (gp < PROT) {
            int n = bestn_s[pl];
            float* dst = out + (size_t)2 * BATCH * PROT + ((size_t)(b * PROT + gp)) * DDIM + dbase;
            const float* src = x + ((size_t)(b * DDIM + dbase)) * NPTS + n;
            #pragma unroll 8
            for (int d = 0; d < 32; ++d) dst[d] = src[(size_t)d * NPTS];
        }
    }
}

extern "C" void kernel_launch(void* const* d_in, const int* in_sizes, int n_in,
                              void* d_out, int out_size, void* d_ws, size_t ws_size,
                              hipStream_t stream) {
    const float* x = (const float*)d_in[0];       // [16,128,56,56]
    const float* proto = (const float*)d_in[1];   // [1,2000,128]
    float* out = (float*)d_out;
    float* ws = (float*)d_ws;

    if (ws_size >= WS_MID) {
        bool big = (ws_size >= WS_BIG);
        float* x2 = ws + WS_X2;
        int* n1w = (int*)(ws + WS_N1);
        int* n2w = (int*)(ws + WS_N2);
        unsigned short* pt = (unsigned short*)(ws + WS_PT);
        unsigned short* xt = (unsigned short*)(ws + WS_XT);
        float* xfT = big ? (ws + WS_XFT) : nullptr;

        pp_p<<<PPAD / 256, 256, 0, stream>>>(proto, pt);
        pp_x<<<dim3(NPTS / 64, BATCH), 256, 0, stream>>>(x, xt, x2, xfT);
        proto_mfma<<<256, 512, 0, stream>>>(xt, pt, x2, n1w, n2w);
        if (big)
            fixup<0><<<(BATCH * PROT) / 4, 256, 0, stream>>>(x, xfT, proto, n1w, n2w, out);
        else
            fixup<1><<<(BATCH * PROT) / 4, 256, 0, stream>>>(x, nullptr, proto, n1w, n2w, out);
    } else {
        float* p2 = ws;
        float* x2 = ws + 2048;
        p2_kernel<<<(PROT + 255) / 256, 256, 0, stream>>>(proto, p2);
        x2_kernel<<<(BATCH * NPTS + 255) / 256, 256, 0, stream>>>(x, x2);
        dim3 grid((PROT + TP - 1) / TP, BATCH);
        proto_main<<<grid, 256, 0, stream>>>(x, proto, p2, x2, out);
    }
}

// Round 5
// 141.585 us; speedup vs baseline: 1.2820x; 1.2820x over previous
//
#include <hip/hip_runtime.h>
#include <hip/hip_bf16.h>
#include <cmath>

#define DDIM 128
#define NPTS 3136   // 56*56
#define NCHUNK 196  // NPTS/16
#define HCHUNK 98   // chunks per n-half
#define BATCH 16
#define PROT 2000
#define PPAD 2048   // 16 tiles * 128

typedef __attribute__((ext_vector_type(8))) short bf16x8;
typedef __attribute__((ext_vector_type(4))) float f32x4;
typedef __attribute__((ext_vector_type(4))) unsigned int u32x4;

// ---- workspace layout (float indices) ----
#define WS_X2   0                      // 50176
#define WS_N1   50176                  // 65536 (2 halves x 16 b x 2048)
#define WS_N2   115712                 // 65536
#define WS_PT   181248                 // 262144 (= 524288 shorts, 2048x256)
#define WS_XT   443392                 // 6422528 (= 16*196*8192 bytes)
#define WS_XFT  6865920                // 6422528 (16*3136*128 f32)
#define WS_MID  ((size_t)6865920 * 4)
#define WS_BIG  ((size_t)13288448 * 4)

// ---------------- bf16 split helpers ----------------
__device__ inline unsigned short bf16rn(float a) {
    unsigned u = __float_as_uint(a);
    unsigned r = u + 0x7FFFu + ((u >> 16) & 1u);
    return (unsigned short)(r >> 16);
}
__device__ inline void split2(float a, unsigned short& h, unsigned short& l) {
    h = bf16rn(a);
    float hf = __uint_as_float(((unsigned)h) << 16);
    l = bf16rn(a - hf);
}

__device__ __forceinline__ void gload_lds16(const void* g, void* l) {
    __builtin_amdgcn_global_load_lds(
        (const __attribute__((address_space(1))) void*)g,
        (__attribute__((address_space(3))) void*)l, 16, 0, 0);
}
__device__ __forceinline__ void gload_lds4(const void* g, void* l) {
    __builtin_amdgcn_global_load_lds(
        (const __attribute__((address_space(1))) void*)g,
        (__attribute__((address_space(3))) void*)l, 4, 0, 0);
}

// ---------------- prototype pre-pass: pt[p][kk][hi/lo][32] ----------------
__global__ void pp_p(const float* __restrict__ proto, unsigned short* __restrict__ pt) {
    int p = blockIdx.x * blockDim.x + threadIdx.x; // 0..2047
    if (p >= PPAD) return;
    int ps = min(p, PROT - 1);
    const float* src = proto + (size_t)ps * DDIM;
    unsigned short* dst = pt + (size_t)p * 256;
    for (int kk = 0; kk < 4; ++kk) {
        for (int j = 0; j < 32; ++j) {
            unsigned short h, l;
            split2(src[kk * 32 + j], h, l);
            dst[kk * 64 + j] = h;
            dst[kk * 64 + 32 + j] = l;
        }
    }
}

// ---------------- x pre-pass ----------------
__global__ __launch_bounds__(256)
void pp_x(const float* __restrict__ x, unsigned short* __restrict__ xt,
          float* __restrict__ x2, float* __restrict__ xfT) {
    __shared__ float xs[DDIM][64];
    int b = blockIdx.y;
    int n0 = blockIdx.x * 64;
    int tid = threadIdx.x;
    {
        int r = tid >> 4, c = tid & 15;
        #pragma unroll
        for (int it = 0; it < 8; ++it) {
            int row = it * 16 + r;
            f32x4 v = *(const f32x4*)(x + ((size_t)(b * DDIM + row)) * NPTS + n0 + c * 4);
            *(f32x4*)(&xs[row][c * 4]) = v;
        }
    }
    __syncthreads();
    if (tid < 64) {
        float s = 0.f;
        #pragma unroll 8
        for (int d = 0; d < DDIM; ++d) { float v = xs[d][tid]; s = fmaf(v, v, s); }
        x2[b * NPTS + n0 + tid] = s;
    }
    int n = tid & 63, kk = tid >> 6;
    int nl = n & 15, ci = (n0 + n) >> 4;
    unsigned int hw[16], lw[16];
    #pragma unroll
    for (int j = 0; j < 16; ++j) {
        unsigned short h0, l0, h1, l1;
        split2(xs[kk * 32 + 2 * j][n], h0, l0);
        split2(xs[kk * 32 + 2 * j + 1][n], h1, l1);
        hw[j] = (unsigned)h0 | ((unsigned)h1 << 16);
        lw[j] = (unsigned)l0 | ((unsigned)l1 << 16);
    }
    char* cb = (char*)xt + ((size_t)b * NCHUNK + ci) * 8192;
    int swz = (nl & 7) << 4;
    #pragma unroll
    for (int q = 0; q < 4; ++q) {
        int ohi = nl * 512 + kk * 128 + q * 16;
        *(u32x4*)(cb + (ohi ^ swz)) = *(u32x4*)(&hw[q * 4]);
        *(u32x4*)(cb + ((ohi + 64) ^ swz)) = *(u32x4*)(&lw[q * 4]);
    }
    if (xfT) {
        float* fo = xfT + ((size_t)b * NPTS + n0 + n) * DDIM + kk * 32;
        #pragma unroll 8
        for (int j = 0; j < 32; ++j) fo[j] = xs[kk * 32 + j][n];
    }
}

// ---------------- main MFMA kernel ----------------
// grid 512 = (16 ptile x 16 b x 2 n-half) XCD-swizzled; block 512 = 8 waves
// = 4 psg x 2 nq. Counted-vmcnt 4-deep pipeline, raw s_barrier (no vmcnt(0)
// drain in the main loop). Each chunk staged ONCE (4 psg waves stage 2KB each).
__global__ __launch_bounds__(512, 4)
void proto_mfma(const unsigned short* __restrict__ xt,
                const unsigned short* __restrict__ pt,
                const float* __restrict__ x2,
                int* __restrict__ n1w, int* __restrict__ n2w) {
    __shared__ __align__(16) char As[4][2][8192];    // 64 KB [buf][nq]
    __shared__ __align__(16) float x2s[2048];        // 8 KB
    __shared__ float rb1[2][128], rb2[2][128];       // 2 KB
    __shared__ int   rn1[2][128], rn2[2][128];       // 2 KB

    int lid = blockIdx.x;                      // 0..511
    int sid = (lid & 7) * 64 + (lid >> 3);     // bijective XCD chunking (512%8==0)
    int b = sid >> 5;
    int rest = sid & 31;
    int pbase = (rest >> 1) * 128;
    int half = rest & 1;

    int tid = threadIdx.x;
    int lane = tid & 63, wave = tid >> 6;
    int psg = wave & 3, nq = wave >> 2;        // 4 p-groups x 2 n-streams
    int l15 = lane & 15, lg = lane >> 4;

    // B fragments: 2 ps x 4 kk x {hi,lo}, resident (64 VGPR)
    bf16x8 Bh[2][4], Bl[2][4];
    #pragma unroll
    for (int ps = 0; ps < 2; ++ps) {
        int p = pbase + psg * 32 + ps * 16 + l15;
        const unsigned short* bp = pt + (size_t)p * 256 + lg * 8;
        #pragma unroll
        for (int kk = 0; kk < 4; ++kk) {
            Bh[ps][kk] = *(const bf16x8*)(bp + kk * 64);
            Bl[ps][kk] = *(const bf16x8*)(bp + kk * 64 + 32);
        }
    }

    const char* srcBase = (const char*)xt + ((size_t)b * NCHUNK + half * HCHUNK) * 8192;
    int preA = ((l15 << 9) | (lg << 4)) ^ ((l15 & 7) << 4);

    float b1[2], b2[2];
    int   i1[2], i2[2];
    #pragma unroll
    for (int ps = 0; ps < 2; ++ps) { b1[ps] = 3e38f; b2[ps] = 3e38f; i1[ps] = 0; i2[ps] = 0; }

    // ---- prologue: stage x2 slice (4 dword-DMAs) + chunks t=0,1,2 (6 DMAs) ----
    {
        const float* xsrc = x2 + (size_t)b * NPTS + half * (HCHUNK * 16);
        #pragma unroll
        for (int it = 0; it < 4; ++it)
            gload_lds4(xsrc + it * 512 + wave * 64 + lane, &x2s[it * 512 + wave * 64]);
    }
    #pragma unroll
    for (int q = 0; q < 3; ++q) {
        int cl = nq + 2 * q;
        const char* src = srcBase + (size_t)cl * 8192 + psg * 2048 + (size_t)lane * 16;
        gload_lds16(src,        &As[q][nq][psg * 2048]);
        gload_lds16(src + 1024, &As[q][nq][psg * 2048 + 1024]);
    }

    // steady state: outstanding = loads for t,t+1,t+2 (6); vmcnt(4) retires t's.
    // Tail issues clamped dummy stages so the count stays uniform (in-order
    // vmcnt retirement makes vmcnt(4) always retire chunk t's loads).
    #pragma unroll 1
    for (int t = 0; t < 49; ++t) {
        asm volatile("s_waitcnt vmcnt(4)" ::: "memory");
        __builtin_amdgcn_s_barrier();
        {
            int cln = nq + 2 * (t + 3);
            cln = cln > 97 ? 97 : cln;         // clamped dummy in tail
            const char* src = srcBase + (size_t)cln * 8192 + psg * 2048 + (size_t)lane * 16;
            char* dst = &As[(t + 3) & 3][nq][psg * 2048];
            gload_lds16(src,        dst);
            gload_lds16(src + 1024, dst + 1024);
        }
        int cl = nq + 2 * t;
        const char* ab = &As[t & 3][nq][0];
        f32x4 xv = *(const f32x4*)&x2s[cl * 16 + lg * 4];

        f32x4 acc[2];
        acc[0] = {0.f, 0.f, 0.f, 0.f};
        acc[1] = {0.f, 0.f, 0.f, 0.f};
        #pragma unroll
        for (int kk = 0; kk < 4; ++kk) {
            bf16x8 Ah = *(const bf16x8*)(ab + (preA ^ (kk * 128)));
            bf16x8 Al = *(const bf16x8*)(ab + (preA ^ (kk * 128 + 64)));
            acc[0] = __builtin_amdgcn_mfma_f32_16x16x32_bf16(Ah, Bh[0][kk], acc[0], 0, 0, 0);
            acc[1] = __builtin_amdgcn_mfma_f32_16x16x32_bf16(Ah, Bh[1][kk], acc[1], 0, 0, 0);
            acc[0] = __builtin_amdgcn_mfma_f32_16x16x32_bf16(Ah, Bl[0][kk], acc[0], 0, 0, 0);
            acc[1] = __builtin_amdgcn_mfma_f32_16x16x32_bf16(Ah, Bl[1][kk], acc[1], 0, 0, 0);
            acc[0] = __builtin_amdgcn_mfma_f32_16x16x32_bf16(Al, Bh[0][kk], acc[0], 0, 0, 0);
            acc[1] = __builtin_amdgcn_mfma_f32_16x16x32_bf16(Al, Bh[1][kk], acc[1], 0, 0, 0);
        }

        int nb = half * (HCHUNK * 16) + cl * 16 + lg * 4;
        #pragma unroll
        for (int ps = 0; ps < 2; ++ps) {
            #pragma unroll
            for (int rr = 0; rr < 4; ++rr) {
                float v = fmaf(acc[ps][rr], -2.f, xv[rr]);   // = d2 - p2[p]
                int n = nb + rr;
                bool c1 = v < b1[ps];
                bool c2 = v < b2[ps];
                i2[ps] = c1 ? i1[ps] : (c2 ? n : i2[ps]);
                b2[ps] = c1 ? b1[ps] : (c2 ? v : b2[ps]);
                i1[ps] = c1 ? n : i1[ps];
                b1[ps] = c1 ? v : b1[ps];
            }
        }
    }
    __syncthreads();   // full drain (incl. dummy DMAs) before reduction

    // ---- reduce across the 4 row-groups (lanes l, l+16, l+32, l+48) ----
    #pragma unroll
    for (int m = 16; m <= 32; m <<= 1) {
        #pragma unroll
        for (int ps = 0; ps < 2; ++ps) {
            float c1v = __shfl_xor(b1[ps], m, 64);
            float c2v = __shfl_xor(b2[ps], m, 64);
            int   cn1 = __shfl_xor(i1[ps], m, 64);
            int   cn2 = __shfl_xor(i2[ps], m, 64);
            bool cl = (c1v < b1[ps]) || (c1v == b1[ps] && cn1 < i1[ps]);
            float m1 = cl ? c1v : b1[ps]; int mn1 = cl ? cn1 : i1[ps];
            float w1 = cl ? b1[ps] : c1v; int wn1 = cl ? i1[ps] : cn1;
            bool tt = (b2[ps] < c2v) || (b2[ps] == c2v && i2[ps] < cn2);
            float s2 = tt ? b2[ps] : c2v; int sn2 = tt ? i2[ps] : cn2;
            bool u = (w1 < s2) || (w1 == s2 && wn1 < sn2);
            b1[ps] = m1; i1[ps] = mn1;
            b2[ps] = u ? w1 : s2; i2[ps] = u ? wn1 : sn2;
        }
    }

    if (lg == 0) {
        #pragma unroll
        for (int ps = 0; ps < 2; ++ps) {
            int idx = psg * 32 + ps * 16 + l15;
            rb1[nq][idx] = b1[ps]; rb2[nq][idx] = b2[ps];
            rn1[nq][idx] = i1[ps]; rn2[nq][idx] = i2[ps];
        }
    }
    __syncthreads();
    if (tid < 128) {
        float B1 = rb1[0][tid], B2 = rb2[0][tid];
        int   N1 = rn1[0][tid], N2 = rn2[0][tid];
        {
            float c1v = rb1[1][tid], c2v = rb2[1][tid];
            int   cn1 = rn1[1][tid], cn2 = rn2[1][tid];
            bool cl = (c1v < B1) || (c1v == B1 && cn1 < N1);
            float m1 = cl ? c1v : B1; int mn1 = cl ? cn1 : N1;
            float w1 = cl ? B1 : c1v; int wn1 = cl ? N1 : cn1;
            bool tt = (B2 < c2v) || (B2 == c2v && N2 < cn2);
            float s2 = tt ? B2 : c2v; int sn2 = tt ? N2 : cn2;
            bool u = (w1 < s2) || (w1 == s2 && wn1 < sn2);
            B1 = m1; N1 = mn1;
            B2 = u ? w1 : s2; N2 = u ? wn1 : sn2;
        }
        size_t o = ((size_t)b * 2 + half) * PPAD + pbase + tid;
        n1w[o] = N1;
        n2w[o] = N2;
    }
}

// ---------------- exact fp32 fixup over 4 candidates + all output writes ----------------
template<int MODE>
__global__ __launch_bounds__(256)
void fixup(const float* __restrict__ x, const float* __restrict__ xfT,
           const float* __restrict__ proto,
           const int* __restrict__ n1w, const int* __restrict__ n2w,
           float* __restrict__ out) {
    int tid = threadIdx.x;
    int lane = tid & 63, wv = tid >> 6;
    long long pair = (long long)blockIdx.x * 4 + wv;
    if (pair >= (long long)BATCH * PROT) return;
    int b = (int)(pair / PROT), p = (int)(pair % PROT);
    int cand[4];
    cand[0] = n1w[((size_t)b * 2 + 0) * PPAD + p];
    cand[1] = n2w[((size_t)b * 2 + 0) * PPAD + p];
    cand[2] = n1w[((size_t)b * 2 + 1) * PPAD + p];
    cand[3] = n2w[((size_t)b * 2 + 1) * PPAD + p];
    int d0 = lane, d1 = lane + 64;
    float pa0 = proto[(size_t)p * DDIM + d0], pa1 = proto[(size_t)p * DDIM + d1];
    float sp2 = pa0 * pa0 + pa1 * pa1;
    float f0[4], f1[4], sxp[4], sx2[4];
    #pragma unroll
    for (int c = 0; c < 4; ++c) {
        int n = cand[c];
        float a0, a1;
        if (MODE == 0) {
            const float* f = xfT + ((size_t)b * NPTS + n) * DDIM;
            a0 = f[d0]; a1 = f[d1];
        } else {
            const float* xb = x + (size_t)b * DDIM * NPTS;
            a0 = xb[(size_t)d0 * NPTS + n]; a1 = xb[(size_t)d1 * NPTS + n];
        }
        f0[c] = a0; f1[c] = a1;
        sxp[c] = a0 * pa0 + a1 * pa1;
        sx2[c] = a0 * a0 + a1 * a1;
    }
    #pragma unroll
    for (int m = 1; m < 64; m <<= 1) {
        sp2 += __shfl_xor(sp2, m, 64);
        #pragma unroll
        for (int c = 0; c < 4; ++c) {
            sxp[c] += __shfl_xor(sxp[c], m, 64);
            sx2[c] += __shfl_xor(sx2[c], m, 64);
        }
    }
    float d2c[4];
    #pragma unroll
    for (int c = 0; c < 4; ++c)
        d2c[c] = fmaxf(sx2[c] + sp2 - 2.f * sxp[c], 0.f);
    float bd = d2c[0]; int bn = cand[0]; float bf0 = f0[0], bf1 = f1[0];
    #pragma unroll
    for (int c = 1; c < 4; ++c) {
        bool w = (d2c[c] < bd) || (d2c[c] == bd && cand[c] < bn);
        bd  = w ? d2c[c] : bd;  bn  = w ? cand[c] : bn;
        bf0 = w ? f0[c] : bf0;  bf1 = w ? f1[c] : bf1;
    }
    float dm = sqrtf(bd);
    float sim = logf((dm + 1.0f) / (dm + 1e-7f));
    if (lane == 0) {
        out[(size_t)b * PROT + p] = sim;
        out[(size_t)BATCH * PROT + (size_t)b * PROT + p] = dm;
    }
    float* fo = out + (size_t)2 * BATCH * PROT + ((size_t)b * PROT + p) * DDIM;
    fo[d0] = bf0;
    fo[d1] = bf1;
}

// ================= fallback fp32 path (round-1, known-good) =================
#define TP 64
#define TN 64
__global__ void p2_kernel(const float* __restrict__ proto, float* __restrict__ p2) {
    int p = blockIdx.x * blockDim.x + threadIdx.x;
    if (p >= PROT) return;
    const float4* pr = reinterpret_cast<const float4*>(proto + (size_t)p * DDIM);
    float s = 0.f;
    #pragma unroll
    for (int i = 0; i < DDIM / 4; ++i) {
        float4 v = pr[i];
        s += v.x * v.x + v.y * v.y + v.z * v.z + v.w * v.w;
    }
    p2[p] = s;
}
__global__ void x2_kernel(const float* __restrict__ x, float* __restrict__ x2) {
    int idx = blockIdx.x * blockDim.x + threadIdx.x;
    if (idx >= BATCH * NPTS) return;
    int b = idx / NPTS, n = idx - b * NPTS;
    const float* xp = x + (size_t)b * DDIM * NPTS + n;
    float s = 0.f;
    #pragma unroll 8
    for (int d = 0; d < DDIM; ++d) { float v = xp[(size_t)d * NPTS]; s += v * v; }
    x2[idx] = s;
}
__global__ __launch_bounds__(256, 2)
void proto_main(const float* __restrict__ x, const float* __restrict__ proto,
                const float* __restrict__ p2, const float* __restrict__ x2,
                float* __restrict__ out) {
    __shared__ __align__(16) float xs[DDIM][TN];
    __shared__ __align__(16) float pst[DDIM][TP];
    __shared__ float p2s[TP];
    __shared__ float x2s[TN];
    __shared__ float red_d2[16][TP];
    __shared__ int   red_n[16][TP];
    __shared__ int   bestn_s[TP];
    const int b = blockIdx.y;
    const int pbase = blockIdx.x * TP;
    const int tid = threadIdx.x;
    {
        #pragma unroll
        for (int it = 0; it < (TP * DDIM / 4) / 256; ++it) {
            int idx = it * 256 + tid;
            int p = idx / (DDIM / 4);
            int dq = idx - p * (DDIM / 4);
            int gp = min(pbase + p, PROT - 1);
            float4 v = reinterpret_cast<const float4*>(proto)[(size_t)gp * (DDIM / 4) + dq];
            pst[dq * 4 + 0][p] = v.x; pst[dq * 4 + 1][p] = v.y;
            pst[dq * 4 + 2][p] = v.z; pst[dq * 4 + 3][p] = v.w;
        }
        if (tid < TP) p2s[tid] = p2[min(pbase + tid, PROT - 1)];
    }
    const int tn = tid >> 4;
    const int tp = tid & 15;
    float best[4]; int bestn[4];
    #pragma unroll
    for (int j = 0; j < 4; ++j) { best[j] = 1e30f; bestn[j] = 0; }
    for (int n0 = 0; n0 < NPTS; n0 += TN) {
        __syncthreads();
        {
            int r = tid >> 4, c = tid & 15;
            #pragma unroll
            for (int it = 0; it < 8; ++it) {
                int row = it * 16 + r;
                float4 v = *reinterpret_cast<const float4*>(
                    x + ((size_t)(b * DDIM + row)) * NPTS + n0 + c * 4);
                *reinterpret_cast<float4*>(&xs[row][c * 4]) = v;
            }
        }
        if (tid < TN) x2s[tid] = x2[b * NPTS + n0 + tid];
        __syncthreads();
        float acc[4][4];
        #pragma unroll
        for (int i = 0; i < 4; ++i)
            #pragma unroll
            for (int j = 0; j < 4; ++j) acc[i][j] = 0.f;
        #pragma unroll 16
        for (int d = 0; d < DDIM; ++d) {
            const float4 a = *reinterpret_cast<const float4*>(&xs[d][tn * 4]);
            const float4 bv = *reinterpret_cast<const float4*>(&pst[d][tp * 4]);
            const float av[4] = {a.x, a.y, a.z, a.w};
            const float bw[4] = {bv.x, bv.y, bv.z, bv.w};
            #pragma unroll
            for (int i = 0; i < 4; ++i)
                #pragma unroll
                for (int j = 0; j < 4; ++j) acc[i][j] = fmaf(av[i], bw[j], acc[i][j]);
        }
        #pragma unroll
        for (int i = 0; i < 4; ++i) {
            float xv = x2s[tn * 4 + i];
            int n = n0 + tn * 4 + i;
            #pragma unroll
            for (int j = 0; j < 4; ++j) {
                float d2 = xv + p2s[tp * 4 + j] - 2.0f * acc[i][j];
                if (d2 < best[j]) { best[j] = d2; bestn[j] = n; }
            }
        }
    }
    #pragma unroll
    for (int j = 0; j < 4; ++j) {
        red_d2[tn][tp * 4 + j] = best[j];
        red_n[tn][tp * 4 + j] = bestn[j];
    }
    __syncthreads();
    if (tid < TP) {
        float bd = red_d2[0][tid]; int bn = red_n[0][tid];
        #pragma unroll
        for (int t = 1; t < 16; ++t) {
            float dv = red_d2[t][tid]; int nv = red_n[t][tid];
            if (dv < bd || (dv == bd && nv < bn)) { bd = dv; bn = nv; }
        }
        int gp = pbase + tid;
        if (gp < PROT) {
            float d2c = fmaxf(bd, 0.f);
            float dmin = sqrtf(d2c);
            float sim = logf((dmin + 1.0f) / (dmin + 1e-7f));
            out[(size_t)b * PROT + gp] = sim;
            out[(size_t)BATCH * PROT + (size_t)b * PROT + gp] = dmin;
        }
        bestn_s[tid] = bn;
    }
    __syncthreads();
    {
        int pl = tid >> 2, dbase = (tid & 3) * 32;
        int gp = pbase + pl;
        if (gp < PROT) {
            int n = bestn_s[pl];
            float* dst = out + (size_t)2 * BATCH * PROT + ((size_t)(b * PROT + gp)) * DDIM + dbase;
            const float* src = x + ((size_t)(b * DDIM + dbase)) * NPTS + n;
            #pragma unroll 8
            for (int d = 0; d < 32; ++d) dst[d] = src[(size_t)d * NPTS];
        }
    }
}

extern "C" void kernel_launch(void* const* d_in, const int* in_sizes, int n_in,
                              void* d_out, int out_size, void* d_ws, size_t ws_size,
                              hipStream_t stream) {
    const float* x = (const float*)d_in[0];       // [16,128,56,56]
    const float* proto = (const float*)d_in[1];   // [1,2000,128]
    float* out = (float*)d_out;
    float* ws = (float*)d_ws;

    if (ws_size >= WS_MID) {
        bool big = (ws_size >= WS_BIG);
        float* x2 = ws + WS_X2;
        int* n1w = (int*)(ws + WS_N1);
        int* n2w = (int*)(ws + WS_N2);
        unsigned short* pt = (unsigned short*)(ws + WS_PT);
        unsigned short* xt = (unsigned short*)(ws + WS_XT);
        float* xfT = big ? (ws + WS_XFT) : nullptr;

        pp_p<<<PPAD / 256, 256, 0, stream>>>(proto, pt);
        pp_x<<<dim3(NPTS / 64, BATCH), 256, 0, stream>>>(x, xt, x2, xfT);
        proto_mfma<<<512, 512, 0, stream>>>(xt, pt, x2, n1w, n2w);
        if (big)
            fixup<0><<<(BATCH * PROT) / 4, 256, 0, stream>>>(x, xfT, proto, n1w, n2w, out);
        else
            fixup<1><<<(BATCH * PROT) / 4, 256, 0, stream>>>(x, nullptr, proto, n1w, n2w, out);
    } else {
        float* p2 = ws;
        float* x2 = ws + 2048;
        p2_kernel<<<(PROT + 255) / 256, 256, 0, stream>>>(proto, p2);
        x2_kernel<<<(BATCH * NPTS + 255) / 256, 256, 0, stream>>>(x, x2);
        dim3 grid((PROT + TP - 1) / TP, BATCH);
        proto_main<<<grid, 256, 0, stream>>>(x, proto, p2, x2, out);
    }
}

// Round 6
// 129.030 us; speedup vs baseline: 1.4068x; 1.0973x over previous
//
#include <hip/hip_runtime.h>
#include <hip/hip_bf16.h>
#include <cmath>

#define DDIM 128
#define NPTS 3136   // 56*56
#define NCHUNK 196  // NPTS/16
#define HCHUNK 98   // chunks per n-half
#define BATCH 16
#define PROT 2000
#define PPAD 2048   // 16 tiles * 128

typedef __attribute__((ext_vector_type(8))) short bf16x8;
typedef __attribute__((ext_vector_type(4))) float f32x4;
typedef __attribute__((ext_vector_type(4))) unsigned int u32x4;

// ---- workspace layout (float indices) ----
#define WS_X2   0                      // 50176
#define WS_N1   50176                  // 65536 (2 halves x 16 b x 2048)
#define WS_N2   115712                 // 65536
#define WS_PT   181248                 // 262144 (= 524288 shorts, 2048x256)
#define WS_XT   443392                 // 6422528 (= 16*196*8192 bytes)
#define WS_XFT  6865920                // 6422528 (16*3136*128 f32)
#define WS_MID  ((size_t)6865920 * 4)
#define WS_BIG  ((size_t)13288448 * 4)

// ---------------- bf16 split helpers ----------------
__device__ inline unsigned short bf16rn(float a) {
    unsigned u = __float_as_uint(a);
    unsigned r = u + 0x7FFFu + ((u >> 16) & 1u);
    return (unsigned short)(r >> 16);
}
__device__ inline void split2(float a, unsigned short& h, unsigned short& l) {
    h = bf16rn(a);
    float hf = __uint_as_float(((unsigned)h) << 16);
    l = bf16rn(a - hf);
}

__device__ __forceinline__ void gload_lds16(const void* g, void* l) {
    __builtin_amdgcn_global_load_lds(
        (const __attribute__((address_space(1))) void*)g,
        (__attribute__((address_space(3))) void*)l, 16, 0, 0);
}
__device__ __forceinline__ void gload_lds4(const void* g, void* l) {
    __builtin_amdgcn_global_load_lds(
        (const __attribute__((address_space(1))) void*)g,
        (__attribute__((address_space(3))) void*)l, 4, 0, 0);
}

__device__ __forceinline__ void top2_update(float v, int n, float& B1, float& B2,
                                            int& I1, int& I2) {
    bool c1 = v < B1;
    bool c2 = v < B2;
    I2 = c1 ? I1 : (c2 ? n : I2);
    B2 = c1 ? B1 : (c2 ? v : B2);
    I1 = c1 ? n : I1;
    B1 = c1 ? v : B1;
}

// ---------------- prototype pre-pass: pt[p][kk][hi/lo][32] ----------------
__global__ void pp_p(const float* __restrict__ proto, unsigned short* __restrict__ pt) {
    int p = blockIdx.x * blockDim.x + threadIdx.x; // 0..2047
    if (p >= PPAD) return;
    int ps = min(p, PROT - 1);
    const float* src = proto + (size_t)ps * DDIM;
    unsigned short* dst = pt + (size_t)p * 256;
    for (int kk = 0; kk < 4; ++kk) {
        for (int j = 0; j < 32; ++j) {
            unsigned short h, l;
            split2(src[kk * 32 + j], h, l);
            dst[kk * 64 + j] = h;
            dst[kk * 64 + 32 + j] = l;
        }
    }
}

// ---------------- x pre-pass ----------------
// xt chunk layout (8KB per 16-n chunk), wave-read-linear:
//   block r = kk*2+s (1KB); within block, lane L = lg*16 + nl holds 16B
//   = {hi|lo} halves of d in [kk*32 + lg*8, +8) for point-row nl.
//   OFF(nl,kk,s,lg) = (kk*2+s)*1024 + lg*256 + nl*16
__global__ __launch_bounds__(256)
void pp_x(const float* __restrict__ x, unsigned short* __restrict__ xt,
          float* __restrict__ x2, float* __restrict__ xfT) {
    __shared__ float xs[DDIM][64];
    int b = blockIdx.y;
    int n0 = blockIdx.x * 64;
    int tid = threadIdx.x;
    {
        int r = tid >> 4, c = tid & 15;
        #pragma unroll
        for (int it = 0; it < 8; ++it) {
            int row = it * 16 + r;
            f32x4 v = *(const f32x4*)(x + ((size_t)(b * DDIM + row)) * NPTS + n0 + c * 4);
            *(f32x4*)(&xs[row][c * 4]) = v;
        }
    }
    __syncthreads();
    if (tid < 64) {
        float s = 0.f;
        #pragma unroll 8
        for (int d = 0; d < DDIM; ++d) { float v = xs[d][tid]; s = fmaf(v, v, s); }
        x2[b * NPTS + n0 + tid] = s;
    }
    int n = tid & 63, kk = tid >> 6;
    int nl = n & 15, ci = (n0 + n) >> 4;
    unsigned int hw[16], lw[16];
    #pragma unroll
    for (int j = 0; j < 16; ++j) {
        unsigned short h0, l0, h1, l1;
        split2(xs[kk * 32 + 2 * j][n], h0, l0);
        split2(xs[kk * 32 + 2 * j + 1][n], h1, l1);
        hw[j] = (unsigned)h0 | ((unsigned)h1 << 16);
        lw[j] = (unsigned)l0 | ((unsigned)l1 << 16);
    }
    char* cb = (char*)xt + ((size_t)b * NCHUNK + ci) * 8192;
    #pragma unroll
    for (int g = 0; g < 4; ++g) {
        *(u32x4*)(cb + (kk * 2 + 0) * 1024 + g * 256 + nl * 16) = *(u32x4*)(&hw[g * 4]);
        *(u32x4*)(cb + (kk * 2 + 1) * 1024 + g * 256 + nl * 16) = *(u32x4*)(&lw[g * 4]);
    }
    if (xfT) {
        float* fo = xfT + ((size_t)b * NPTS + n0 + n) * DDIM + kk * 32;
        #pragma unroll 8
        for (int j = 0; j < 32; ++j) fo[j] = xs[kk * 32 + j][n];
    }
}

// ---------------- main MFMA kernel ----------------
// grid 512 = (16 ptile x 16 b x 2 n-half) XCD-swizzled; block 512 = 8 waves
// = 4 psg x 2 nq. Counted-vmcnt 4-deep pipeline; loop unrolled x4 so every
// ds_read is vaddr=lane*16 + compile-time imm (conflict-minimal, zero addr VALU).
__global__ __launch_bounds__(512, 4)
void proto_mfma(const unsigned short* __restrict__ xt,
                const unsigned short* __restrict__ pt,
                const float* __restrict__ x2,
                int* __restrict__ n1w, int* __restrict__ n2w) {
    // hand-placed LDS: [0,8K) x2s | [8K,72K) As[4buf][2nq][8K] | [72K..76K) red
    __shared__ __align__(16) char LDS[77824];
    float* x2s = (float*)LDS;
    char*  AsB = LDS + 8192;
    float* rb1 = (float*)(LDS + 73728);   // [2][128]
    float* rb2 = rb1 + 256;
    int*   rn1 = (int*)(rb2 + 256);
    int*   rn2 = rn1 + 256;

    int lid = blockIdx.x;                      // 0..511
    int sid = (lid & 7) * 64 + (lid >> 3);     // bijective XCD chunking (512%8==0)
    int b = sid >> 5;
    int rest = sid & 31;
    int pbase = (rest >> 1) * 128;
    int half = rest & 1;

    int tid = threadIdx.x;
    int lane = tid & 63, wave = tid >> 6;
    int psg = wave & 3, nq = wave >> 2;        // 4 p-groups x 2 n-streams
    int l15 = lane & 15, lg = lane >> 4;

    // B fragments: 2 ps x 4 kk x {hi,lo}, resident (64 VGPR)
    bf16x8 Bh[2][4], Bl[2][4];
    #pragma unroll
    for (int ps = 0; ps < 2; ++ps) {
        int p = pbase + psg * 32 + ps * 16 + l15;
        const unsigned short* bp = pt + (size_t)p * 256 + lg * 8;
        #pragma unroll
        for (int kk = 0; kk < 4; ++kk) {
            Bh[ps][kk] = *(const bf16x8*)(bp + kk * 64);
            Bl[ps][kk] = *(const bf16x8*)(bp + kk * 64 + 32);
        }
    }

    const char* srcBase = (const char*)xt + ((size_t)b * NCHUNK + half * HCHUNK) * 8192;
    const char* aread = AsB + nq * 8192 + lane * 16;   // + u*16384 + (kk*2+s)*1024
    const int halfOfs = half * (HCHUNK * 16);

    float b1[2], b2[2];
    int   i1[2], i2[2];
    #pragma unroll
    for (int ps = 0; ps < 2; ++ps) { b1[ps] = 3e38f; b2[ps] = 3e38f; i1[ps] = 0; i2[ps] = 0; }

    // ---- prologue: x2 slice (4 dword-DMAs) + chunks t=0,1,2 (6 DMAs) ----
    {
        const float* xsrc = x2 + (size_t)b * NPTS + half * (HCHUNK * 16);
        #pragma unroll
        for (int it = 0; it < 4; ++it)
            gload_lds4(xsrc + it * 512 + wave * 64 + lane, (char*)x2s + (it * 512 + wave * 64) * 4);
    }
    #pragma unroll
    for (int q = 0; q < 3; ++q) {
        const char* src = srcBase + (size_t)(nq + 2 * q) * 8192 + psg * 2048 + (size_t)lane * 16;
        char* dst = AsB + q * 16384 + nq * 8192 + psg * 2048;
        gload_lds16(src, dst);
        gload_lds16(src + 1024, dst + 1024);
    }

    // Body: steady-state 6 outstanding chunk-DMAs; vmcnt(4) retires chunk t's.
    // U must be a literal (buf select folds into ds_read imm offsets).
#define PMF_BODY(T, U)                                                              \
    {                                                                               \
        asm volatile("s_waitcnt vmcnt(4)" ::: "memory");                            \
        __builtin_amdgcn_s_barrier();                                               \
        int cln = nq + 2 * ((T) + 3);                                               \
        cln = cln > 97 ? 97 : cln;                                                  \
        const char* psrc = srcBase + (size_t)cln * 8192 + psg * 2048 + (size_t)lane * 16; \
        char* pdst = AsB + (((U) + 3) & 3) * 16384 + nq * 8192 + psg * 2048;        \
        gload_lds16(psrc, pdst);                                                    \
        gload_lds16(psrc + 1024, pdst + 1024);                                      \
        int cl = nq + 2 * (T);                                                      \
        f32x4 xv = *(const f32x4*)&x2s[cl * 16 + lg * 4];                           \
        const char* ar = aread + (U) * 16384;                                       \
        f32x4 acc0 = {0.f, 0.f, 0.f, 0.f};                                          \
        f32x4 acc1 = {0.f, 0.f, 0.f, 0.f};                                          \
        __builtin_amdgcn_s_setprio(1);                                              \
        _Pragma("unroll")                                                           \
        for (int kk = 0; kk < 4; ++kk) {                                            \
            bf16x8 Ah = *(const bf16x8*)(ar + kk * 2048);                           \
            bf16x8 Al = *(const bf16x8*)(ar + kk * 2048 + 1024);                    \
            acc0 = __builtin_amdgcn_mfma_f32_16x16x32_bf16(Ah, Bh[0][kk], acc0, 0, 0, 0); \
            acc1 = __builtin_amdgcn_mfma_f32_16x16x32_bf16(Ah, Bh[1][kk], acc1, 0, 0, 0); \
            acc0 = __builtin_amdgcn_mfma_f32_16x16x32_bf16(Ah, Bl[0][kk], acc0, 0, 0, 0); \
            acc1 = __builtin_amdgcn_mfma_f32_16x16x32_bf16(Ah, Bl[1][kk], acc1, 0, 0, 0); \
            acc0 = __builtin_amdgcn_mfma_f32_16x16x32_bf16(Al, Bh[0][kk], acc0, 0, 0, 0); \
            acc1 = __builtin_amdgcn_mfma_f32_16x16x32_bf16(Al, Bh[1][kk], acc1, 0, 0, 0); \
        }                                                                           \
        __builtin_amdgcn_s_setprio(0);                                              \
        int nb = halfOfs + cl * 16 + lg * 4;                                        \
        _Pragma("unroll")                                                           \
        for (int rr = 0; rr < 4; ++rr) {                                            \
            top2_update(fmaf(acc0[rr], -2.f, xv[rr]), nb + rr, b1[0], b2[0], i1[0], i2[0]); \
            top2_update(fmaf(acc1[rr], -2.f, xv[rr]), nb + rr, b1[1], b2[1], i1[1], i2[1]); \
        }                                                                           \
    }

    #pragma unroll 1
    for (int t0 = 0; t0 < 48; t0 += 4) {
        PMF_BODY(t0 + 0, 0)
        PMF_BODY(t0 + 1, 1)
        PMF_BODY(t0 + 2, 2)
        PMF_BODY(t0 + 3, 3)
    }
    PMF_BODY(48, 0)
#undef PMF_BODY
    __syncthreads();   // full drain (incl. dummy DMAs) before reduction

    // ---- reduce across the 4 row-groups (lanes l, l+16, l+32, l+48) ----
    #pragma unroll
    for (int m = 16; m <= 32; m <<= 1) {
        #pragma unroll
        for (int ps = 0; ps < 2; ++ps) {
            float c1v = __shfl_xor(b1[ps], m, 64);
            float c2v = __shfl_xor(b2[ps], m, 64);
            int   cn1 = __shfl_xor(i1[ps], m, 64);
            int   cn2 = __shfl_xor(i2[ps], m, 64);
            bool cl = (c1v < b1[ps]) || (c1v == b1[ps] && cn1 < i1[ps]);
            float m1 = cl ? c1v : b1[ps]; int mn1 = cl ? cn1 : i1[ps];
            float w1 = cl ? b1[ps] : c1v; int wn1 = cl ? i1[ps] : cn1;
            bool tt = (b2[ps] < c2v) || (b2[ps] == c2v && i2[ps] < cn2);
            float s2 = tt ? b2[ps] : c2v; int sn2 = tt ? i2[ps] : cn2;
            bool u = (w1 < s2) || (w1 == s2 && wn1 < sn2);
            b1[ps] = m1; i1[ps] = mn1;
            b2[ps] = u ? w1 : s2; i2[ps] = u ? wn1 : sn2;
        }
    }

    if (lg == 0) {
        #pragma unroll
        for (int ps = 0; ps < 2; ++ps) {
            int idx = psg * 32 + ps * 16 + l15;
            rb1[nq * 128 + idx] = b1[ps]; rb2[nq * 128 + idx] = b2[ps];
            rn1[nq * 128 + idx] = i1[ps]; rn2[nq * 128 + idx] = i2[ps];
        }
    }
    __syncthreads();
    if (tid < 128) {
        float B1 = rb1[tid], B2 = rb2[tid];
        int   N1 = rn1[tid], N2 = rn2[tid];
        {
            float c1v = rb1[128 + tid], c2v = rb2[128 + tid];
            int   cn1 = rn1[128 + tid], cn2 = rn2[128 + tid];
            bool cl = (c1v < B1) || (c1v == B1 && cn1 < N1);
            float m1 = cl ? c1v : B1; int mn1 = cl ? cn1 : N1;
            float w1 = cl ? B1 : c1v; int wn1 = cl ? N1 : cn1;
            bool tt = (B2 < c2v) || (B2 == c2v && N2 < cn2);
            float s2 = tt ? B2 : c2v; int sn2 = tt ? N2 : cn2;
            bool u = (w1 < s2) || (w1 == s2 && wn1 < sn2);
            B1 = m1; N1 = mn1;
            B2 = u ? w1 : s2; N2 = u ? wn1 : sn2;
        }
        size_t o = ((size_t)b * 2 + half) * PPAD + pbase + tid;
        n1w[o] = N1;
        n2w[o] = N2;
    }
}

// ---------------- exact fp32 fixup over 4 candidates + all output writes ----------------
template<int MODE>
__global__ __launch_bounds__(256)
void fixup(const float* __restrict__ x, const float* __restrict__ xfT,
           const float* __restrict__ proto,
           const int* __restrict__ n1w, const int* __restrict__ n2w,
           float* __restrict__ out) {
    int tid = threadIdx.x;
    int lane = tid & 63, wv = tid >> 6;
    long long pair = (long long)blockIdx.x * 4 + wv;
    if (pair >= (long long)BATCH * PROT) return;
    int b = (int)(pair / PROT), p = (int)(pair % PROT);
    int cand[4];
    cand[0] = n1w[((size_t)b * 2 + 0) * PPAD + p];
    cand[1] = n2w[((size_t)b * 2 + 0) * PPAD + p];
    cand[2] = n1w[((size_t)b * 2 + 1) * PPAD + p];
    cand[3] = n2w[((size_t)b * 2 + 1) * PPAD + p];
    int d0 = lane, d1 = lane + 64;
    float pa0 = proto[(size_t)p * DDIM + d0], pa1 = proto[(size_t)p * DDIM + d1];
    float sp2 = pa0 * pa0 + pa1 * pa1;
    float f0[4], f1[4], sxp[4], sx2[4];
    #pragma unroll
    for (int c = 0; c < 4; ++c) {
        int n = cand[c];
        float a0, a1;
        if (MODE == 0) {
            const float* f = xfT + ((size_t)b * NPTS + n) * DDIM;
            a0 = f[d0]; a1 = f[d1];
        } else {
            const float* xb = x + (size_t)b * DDIM * NPTS;
            a0 = xb[(size_t)d0 * NPTS + n]; a1 = xb[(size_t)d1 * NPTS + n];
        }
        f0[c] = a0; f1[c] = a1;
        sxp[c] = a0 * pa0 + a1 * pa1;
        sx2[c] = a0 * a0 + a1 * a1;
    }
    #pragma unroll
    for (int m = 1; m < 64; m <<= 1) {
        sp2 += __shfl_xor(sp2, m, 64);
        #pragma unroll
        for (int c = 0; c < 4; ++c) {
            sxp[c] += __shfl_xor(sxp[c], m, 64);
            sx2[c] += __shfl_xor(sx2[c], m, 64);
        }
    }
    float d2c[4];
    #pragma unroll
    for (int c = 0; c < 4; ++c)
        d2c[c] = fmaxf(sx2[c] + sp2 - 2.f * sxp[c], 0.f);
    float bd = d2c[0]; int bn = cand[0]; float bf0 = f0[0], bf1 = f1[0];
    #pragma unroll
    for (int c = 1; c < 4; ++c) {
        bool w = (d2c[c] < bd) || (d2c[c] == bd && cand[c] < bn);
        bd  = w ? d2c[c] : bd;  bn  = w ? cand[c] : bn;
        bf0 = w ? f0[c] : bf0;  bf1 = w ? f1[c] : bf1;
    }
    float dm = sqrtf(bd);
    float sim = logf((dm + 1.0f) / (dm + 1e-7f));
    if (lane == 0) {
        out[(size_t)b * PROT + p] = sim;
        out[(size_t)BATCH * PROT + (size_t)b * PROT + p] = dm;
    }
    float* fo = out + (size_t)2 * BATCH * PROT + ((size_t)b * PROT + p) * DDIM;
    fo[d0] = bf0;
    fo[d1] = bf1;
}

// ================= fallback fp32 path (round-1, known-good) =================
#define TP 64
#define TN 64
__global__ void p2_kernel(const float* __restrict__ proto, float* __restrict__ p2) {
    int p = blockIdx.x * blockDim.x + threadIdx.x;
    if (p >= PROT) return;
    const float4* pr = reinterpret_cast<const float4*>(proto + (size_t)p * DDIM);
    float s = 0.f;
    #pragma unroll
    for (int i = 0; i < DDIM / 4; ++i) {
        float4 v = pr[i];
        s += v.x * v.x + v.y * v.y + v.z * v.z + v.w * v.w;
    }
    p2[p] = s;
}
__global__ void x2_kernel(const float* __restrict__ x, float* __restrict__ x2) {
    int idx = blockIdx.x * blockDim.x + threadIdx.x;
    if (idx >= BATCH * NPTS) return;
    int b = idx / NPTS, n = idx - b * NPTS;
    const float* xp = x + (size_t)b * DDIM * NPTS + n;
    float s = 0.f;
    #pragma unroll 8
    for (int d = 0; d < DDIM; ++d) { float v = xp[(size_t)d * NPTS]; s += v * v; }
    x2[idx] = s;
}
__global__ __launch_bounds__(256, 2)
void proto_main(const float* __restrict__ x, const float* __restrict__ proto,
                const float* __restrict__ p2, const float* __restrict__ x2,
                float* __restrict__ out) {
    __shared__ __align__(16) float xs[DDIM][TN];
    __shared__ __align__(16) float pst[DDIM][TP];
    __shared__ float p2s[TP];
    __shared__ float x2s[TN];
    __shared__ float red_d2[16][TP];
    __shared__ int   red_n[16][TP];
    __shared__ int   bestn_s[TP];
    const int b = blockIdx.y;
    const int pbase = blockIdx.x * TP;
    const int tid = threadIdx.x;
    {
        #pragma unroll
        for (int it = 0; it < (TP * DDIM / 4) / 256; ++it) {
            int idx = it * 256 + tid;
            int p = idx / (DDIM / 4);
            int dq = idx - p * (DDIM / 4);
            int gp = min(pbase + p, PROT - 1);
            float4 v = reinterpret_cast<const float4*>(proto)[(size_t)gp * (DDIM / 4) + dq];
            pst[dq * 4 + 0][p] = v.x; pst[dq * 4 + 1][p] = v.y;
            pst[dq * 4 + 2][p] = v.z; pst[dq * 4 + 3][p] = v.w;
        }
        if (tid < TP) p2s[tid] = p2[min(pbase + tid, PROT - 1)];
    }
    const int tn = tid >> 4;
    const int tp = tid & 15;
    float best[4]; int bestn[4];
    #pragma unroll
    for (int j = 0; j < 4; ++j) { best[j] = 1e30f; bestn[j] = 0; }
    for (int n0 = 0; n0 < NPTS; n0 += TN) {
        __syncthreads();
        {
            int r = tid >> 4, c = tid & 15;
            #pragma unroll
            for (int it = 0; it < 8; ++it) {
                int row = it * 16 + r;
                float4 v = *reinterpret_cast<const float4*>(
                    x + ((size_t)(b * DDIM + row)) * NPTS + n0 + c * 4);
                *reinterpret_cast<float4*>(&xs[row][c * 4]) = v;
            }
        }
        if (tid < TN) x2s[tid] = x2[b * NPTS + n0 + tid];
        __syncthreads();
        float acc[4][4];
        #pragma unroll
        for (int i = 0; i < 4; ++i)
            #pragma unroll
            for (int j = 0; j < 4; ++j) acc[i][j] = 0.f;
        #pragma unroll 16
        for (int d = 0; d < DDIM; ++d) {
            const float4 a = *reinterpret_cast<const float4*>(&xs[d][tn * 4]);
            const float4 bv = *reinterpret_cast<const float4*>(&pst[d][tp * 4]);
            const float av[4] = {a.x, a.y, a.z, a.w};
            const float bw[4] = {bv.x, bv.y, bv.z, bv.w};
            #pragma unroll
            for (int i = 0; i < 4; ++i)
                #pragma unroll
                for (int j = 0; j < 4; ++j) acc[i][j] = fmaf(av[i], bw[j], acc[i][j]);
        }
        #pragma unroll
        for (int i = 0; i < 4; ++i) {
            float xv = x2s[tn * 4 + i];
            int n = n0 + tn * 4 + i;
            #pragma unroll
            for (int j = 0; j < 4; ++j) {
                float d2 = xv + p2s[tp * 4 + j] - 2.0f * acc[i][j];
                if (d2 < best[j]) { best[j] = d2; bestn[j] = n; }
            }
        }
    }
    #pragma unroll
    for (int j = 0; j < 4; ++j) {
        red_d2[tn][tp * 4 + j] = best[j];
        red_n[tn][tp * 4 + j] = bestn[j];
    }
    __syncthreads();
    if (tid < TP) {
        float bd = red_d2[0][tid]; int bn = red_n[0][tid];
        #pragma unroll
        for (int t = 1; t < 16; ++t) {
            float dv = red_d2[t][tid]; int nv = red_n[t][tid];
            if (dv < bd || (dv == bd && nv < bn)) { bd = dv; bn = nv; }
        }
        int gp = pbase + tid;
        if (gp < PROT) {
            float d2c = fmaxf(bd, 0.f);
            float dmin = sqrtf(d2c);
            float sim = logf((dmin + 1.0f) / (dmin + 1e-7f));
            out[(size_t)b * PROT + gp] = sim;
            out[(size_t)BATCH * PROT + (size_t)b * PROT + gp] = dmin;
        }
        bestn_s[tid] = bn;
    }
    __syncthreads();
    {
        int pl = tid >> 2, dbase = (tid & 3) * 32;
        int gp = pbase + pl;
        if (gp < PROT) {
            int n = bestn_s[pl];
            float* dst = out + (size_t)2 * BATCH * PROT + ((size_t)(b * PROT + gp)) * DDIM + dbase;
            const float* src = x + ((size_t)(b * DDIM + dbase)) * NPTS + n;
            #pragma unroll 8
            for (int d = 0; d < 32; ++d) dst[d] = src[(size_t)d * NPTS];
        }
    }
}

extern "C" void kernel_launch(void* const* d_in, const int* in_sizes, int n_in,
                              void* d_out, int out_size, void* d_ws, size_t ws_size,
                              hipStream_t stream) {
    const float* x = (const float*)d_in[0];       // [16,128,56,56]
    const float* proto = (const float*)d_in[1];   // [1,2000,128]
    float* out = (float*)d_out;
    float* ws = (float*)d_ws;

    if (ws_size >= WS_MID) {
        bool big = (ws_size >= WS_BIG);
        float* x2 = ws + WS_X2;
        int* n1w = (int*)(ws + WS_N1);
        int* n2w = (int*)(ws + WS_N2);
        unsigned short* pt = (unsigned short*)(ws + WS_PT);
        unsigned short* xt = (unsigned short*)(ws + WS_XT);
        float* xfT = big ? (ws + WS_XFT) : nullptr;

        pp_p<<<PPAD / 256, 256, 0, stream>>>(proto, pt);
        pp_x<<<dim3(NPTS / 64, BATCH), 256, 0, stream>>>(x, xt, x2, xfT);
        proto_mfma<<<512, 512, 0, stream>>>(xt, pt, x2, n1w, n2w);
        if (big)
            fixup<0><<<(BATCH * PROT) / 4, 256, 0, stream>>>(x, xfT, proto, n1w, n2w, out);
        else
            fixup<1><<<(BATCH * PROT) / 4, 256, 0, stream>>>(x, nullptr, proto, n1w, n2w, out);
    } else {
        float* p2 = ws;
        float* x2 = ws + 2048;
        p2_kernel<<<(PROT + 255) / 256, 256, 0, stream>>>(proto, p2);
        x2_kernel<<<(BATCH * NPTS + 255) / 256, 256, 0, stream>>>(x, x2);
        dim3 grid((PROT + TP - 1) / TP, BATCH);
        proto_main<<<grid, 256, 0, stream>>>(x, proto, p2, x2, out);
    }
}

// Round 7
// 101.037 us; speedup vs baseline: 1.7966x; 1.2771x over previous
//
#include <hip/hip_runtime.h>
#include <hip/hip_bf16.h>
#include <cmath>

#define DDIM 128
#define NPTS 3136   // 56*56
#define NCHUNK 196  // NPTS/16
#define HCHUNK 98   // chunks per n-half
#define BATCH 16
#define PROT 2000
#define PPAD 2048   // 16 tiles * 128

typedef __attribute__((ext_vector_type(8))) short bf16x8;
typedef __attribute__((ext_vector_type(4))) float f32x4;
typedef __attribute__((ext_vector_type(4))) unsigned int u32x4;

// ---- workspace layout (float indices) ----
#define WS_X2   0                      // 50176
#define WS_N1   50176                  // 65536 (2 halves x 16 b x 2048)
#define WS_N2   115712                 // 65536
#define WS_P2   181248                 // 2048
#define WS_PT   183296                 // 131072 floats (= 262144 shorts, 2048x128)
#define WS_XT   314368                 // 3211264 floats (= 16*196*4096 bytes)
#define WS_XFT  3525632                // 6422528 (16*3136*128 f32)
#define WS_MID  ((size_t)3525632 * 4)
#define WS_BIG  ((size_t)9948160 * 4)

// ---------------- bf16 helpers ----------------
__device__ inline unsigned short bf16rn(float a) {
    unsigned u = __float_as_uint(a);
    unsigned r = u + 0x7FFFu + ((u >> 16) & 1u);
    return (unsigned short)(r >> 16);
}

__device__ __forceinline__ void gload_lds16(const void* g, void* l) {
    __builtin_amdgcn_global_load_lds(
        (const __attribute__((address_space(1))) void*)g,
        (__attribute__((address_space(3))) void*)l, 16, 0, 0);
}
__device__ __forceinline__ void gload_lds4(const void* g, void* l) {
    __builtin_amdgcn_global_load_lds(
        (const __attribute__((address_space(1))) void*)g,
        (__attribute__((address_space(3))) void*)l, 4, 0, 0);
}

// ---------------- prototype pre-pass: pt[p][kk][32] bf16-rn + exact p2 ----------------
__global__ void pp_p(const float* __restrict__ proto, unsigned short* __restrict__ pt,
                     float* __restrict__ p2w) {
    int p = blockIdx.x * blockDim.x + threadIdx.x; // 0..2047
    if (p >= PPAD) return;
    int ps = min(p, PROT - 1);
    const float* src = proto + (size_t)ps * DDIM;
    unsigned short* dst = pt + (size_t)p * 128;
    float s = 0.f;
    for (int j = 0; j < DDIM; ++j) {
        float v = src[j];
        s = fmaf(v, v, s);
        dst[j] = bf16rn(v);
    }
    p2w[p] = s;
}

// ---------------- x pre-pass ----------------
// xt chunk layout (4KB per 16-n chunk), wave-read-linear:
//   OFF(nl,kk,lg) = kk*1024 + lg*256 + nl*16 : 8 bf16 of d in [kk*32+lg*8, +8), row nl
__global__ __launch_bounds__(256)
void pp_x(const float* __restrict__ x, unsigned short* __restrict__ xt,
          float* __restrict__ x2, float* __restrict__ xfT) {
    __shared__ float xs[DDIM][64];
    int b = blockIdx.y;
    int n0 = blockIdx.x * 64;
    int tid = threadIdx.x;
    {
        int r = tid >> 4, c = tid & 15;
        #pragma unroll
        for (int it = 0; it < 8; ++it) {
            int row = it * 16 + r;
            f32x4 v = *(const f32x4*)(x + ((size_t)(b * DDIM + row)) * NPTS + n0 + c * 4);
            *(f32x4*)(&xs[row][c * 4]) = v;
        }
    }
    __syncthreads();
    if (tid < 64) {
        float s = 0.f;
        #pragma unroll 8
        for (int d = 0; d < DDIM; ++d) { float v = xs[d][tid]; s = fmaf(v, v, s); }
        x2[b * NPTS + n0 + tid] = s;
    }
    int n = tid & 63, kk = tid >> 6;
    int nl = n & 15, ci = (n0 + n) >> 4;
    unsigned int hw[16];
    #pragma unroll
    for (int j = 0; j < 16; ++j) {
        unsigned short h0 = bf16rn(xs[kk * 32 + 2 * j][n]);
        unsigned short h1 = bf16rn(xs[kk * 32 + 2 * j + 1][n]);
        hw[j] = (unsigned)h0 | ((unsigned)h1 << 16);
    }
    char* cb = (char*)xt + ((size_t)b * NCHUNK + ci) * 4096;
    #pragma unroll
    for (int g = 0; g < 4; ++g)
        *(u32x4*)(cb + kk * 1024 + g * 256 + nl * 16) = *(u32x4*)(&hw[g * 4]);
    if (xfT) {
        float* fo = xfT + ((size_t)b * NPTS + n0 + n) * DDIM + kk * 32;
        #pragma unroll 8
        for (int j = 0; j < 32; ++j) fo[j] = xs[kk * 32 + j][n];
    }
}

// ---------------- main MFMA kernel (single-bf16 select, packed u32 keys) ----------------
// grid 512 = (16 ptile x 16 b x 2 n-half) XCD-swizzled; block 512 = 8 waves
// = 4 psg x 2 nq. Counted-vmcnt (2) pipeline, 1 DMA/wave/iter, 4-deep buffers.
__global__ __launch_bounds__(512, 6)
void proto_mfma(const unsigned short* __restrict__ xt,
                const unsigned short* __restrict__ pt,
                const float* __restrict__ x2, const float* __restrict__ p2w,
                int* __restrict__ n1w, int* __restrict__ n2w) {
    // hand-placed LDS: [0,8K) x2s | [8K,40K) As[4buf][2nq][4K] | [40K,42K) red
    __shared__ __align__(16) char LDS[43008];
    float* x2s = (float*)LDS;
    char*  AsB = LDS + 8192;
    unsigned* rk1 = (unsigned*)(LDS + 40960);   // [2][128]
    unsigned* rk2 = rk1 + 256;

    int lid = blockIdx.x;                      // 0..511
    int sid = (lid & 7) * 64 + (lid >> 3);     // bijective XCD chunking (512%8==0)
    int b = sid >> 5;
    int rest = sid & 31;
    int pbase = (rest >> 1) * 128;
    int half = rest & 1;

    int tid = threadIdx.x;
    int lane = tid & 63, wave = tid >> 6;
    int psg = wave & 3, nq = wave >> 2;        // 4 p-groups x 2 n-streams
    int l15 = lane & 15, lg = lane >> 4;

    // B fragments: 2 ps x 4 kk = 32 VGPR, resident; exact p2 per slot
    bf16x8 Bh[2][4];
    float p2r[2];
    #pragma unroll
    for (int ps = 0; ps < 2; ++ps) {
        int p = pbase + psg * 32 + ps * 16 + l15;
        const unsigned short* bp = pt + (size_t)p * 128 + lg * 8;
        #pragma unroll
        for (int kk = 0; kk < 4; ++kk)
            Bh[ps][kk] = *(const bf16x8*)(bp + kk * 32);
        p2r[ps] = p2w[p];
    }

    const char* srcBase = (const char*)xt + ((size_t)b * NCHUNK + half * HCHUNK) * 4096;
    const char* aread = AsB + nq * 4096 + lane * 16;   // + u*8192 + kk*1024
    const int halfOfs = half * (HCHUNK * 16);

    unsigned K1[2], K2[2];
    K1[0] = K1[1] = 0xFFFFFFFFu;
    K2[0] = K2[1] = 0xFFFFFFFFu;

    // ---- prologue: x2 slice (4 dword-DMAs) + chunks t=0,1,2 (1 DMA each) ----
    {
        const float* xsrc = x2 + (size_t)b * NPTS + half * (HCHUNK * 16);
        #pragma unroll
        for (int it = 0; it < 4; ++it)
            gload_lds4(xsrc + it * 512 + wave * 64 + lane, (char*)x2s + (it * 512 + wave * 64) * 4);
    }
    #pragma unroll
    for (int q = 0; q < 3; ++q)
        gload_lds16(srcBase + (size_t)(nq + 2 * q) * 4096 + psg * 1024 + (size_t)lane * 16,
                    AsB + q * 8192 + nq * 4096 + psg * 1024);

    // Body: 1 chunk-DMA per wave per iter; vmcnt(2) guarantees chunk t landed
    // (in-order retirement; any compiler-inserted loads only over-wait).
#define PMF_BODY(T, U)                                                              \
    {                                                                               \
        asm volatile("s_waitcnt vmcnt(2)" ::: "memory");                            \
        __builtin_amdgcn_s_barrier();                                               \
        int cln = nq + 2 * ((T) + 3);                                               \
        cln = cln > 97 ? 97 : cln;                                                  \
        gload_lds16(srcBase + (size_t)cln * 4096 + psg * 1024 + (size_t)lane * 16,  \
                    AsB + (((U) + 3) & 3) * 8192 + nq * 4096 + psg * 1024);         \
        int cl = nq + 2 * (T);                                                      \
        f32x4 xv = *(const f32x4*)&x2s[cl * 16 + lg * 4];                           \
        f32x4 xp0 = xv + p2r[0];                                                    \
        f32x4 xp1 = xv + p2r[1];                                                    \
        const char* ar = aread + (U) * 8192;                                        \
        f32x4 acc0 = {0.f, 0.f, 0.f, 0.f};                                          \
        f32x4 acc1 = {0.f, 0.f, 0.f, 0.f};                                          \
        __builtin_amdgcn_s_setprio(1);                                              \
        _Pragma("unroll")                                                           \
        for (int kk = 0; kk < 4; ++kk) {                                            \
            bf16x8 Ah = *(const bf16x8*)(ar + kk * 1024);                           \
            acc0 = __builtin_amdgcn_mfma_f32_16x16x32_bf16(Ah, Bh[0][kk], acc0, 0, 0, 0); \
            acc1 = __builtin_amdgcn_mfma_f32_16x16x32_bf16(Ah, Bh[1][kk], acc1, 0, 0, 0); \
        }                                                                           \
        __builtin_amdgcn_s_setprio(0);                                              \
        int nb = halfOfs + cl * 16 + lg * 4;                                        \
        _Pragma("unroll")                                                           \
        for (int rr = 0; rr < 4; ++rr) {                                            \
            float f0 = fmaxf(fmaf(acc0[rr], -2.f, xp0[rr]), 0.f);                   \
            float f1 = fmaxf(fmaf(acc1[rr], -2.f, xp1[rr]), 0.f);                   \
            unsigned k0 = (__float_as_uint(f0) & 0xFFFFF000u) | (unsigned)(nb + rr); \
            unsigned k1 = (__float_as_uint(f1) & 0xFFFFF000u) | (unsigned)(nb + rr); \
            bool a1 = k0 < K1[0], a2 = k0 < K2[0];                                  \
            K2[0] = a1 ? K1[0] : (a2 ? k0 : K2[0]);                                 \
            K1[0] = a1 ? k0 : K1[0];                                                \
            bool d1 = k1 < K1[1], d2 = k1 < K2[1];                                  \
            K2[1] = d1 ? K1[1] : (d2 ? k1 : K2[1]);                                 \
            K1[1] = d1 ? k1 : K1[1];                                                \
        }                                                                           \
    }

    #pragma unroll 1
    for (int t0 = 0; t0 < 48; t0 += 4) {
        PMF_BODY(t0 + 0, 0)
        PMF_BODY(t0 + 1, 1)
        PMF_BODY(t0 + 2, 2)
        PMF_BODY(t0 + 3, 3)
    }
    PMF_BODY(48, 0)
#undef PMF_BODY
    __syncthreads();   // full drain (incl. dummy DMAs) before reduction

    // ---- reduce across the 4 row-groups (lanes l, l+16, l+32, l+48) ----
    #pragma unroll
    for (int m = 16; m <= 32; m <<= 1) {
        #pragma unroll
        for (int ps = 0; ps < 2; ++ps) {
            unsigned c1 = (unsigned)__shfl_xor((int)K1[ps], m, 64);
            unsigned c2 = (unsigned)__shfl_xor((int)K2[ps], m, 64);
            unsigned w  = max(K1[ps], c1);
            K1[ps] = min(K1[ps], c1);
            K2[ps] = min(w, min(K2[ps], c2));
        }
    }

    if (lg == 0) {
        #pragma unroll
        for (int ps = 0; ps < 2; ++ps) {
            int idx = psg * 32 + ps * 16 + l15;
            rk1[nq * 128 + idx] = K1[ps];
            rk2[nq * 128 + idx] = K2[ps];
        }
    }
    __syncthreads();
    if (tid < 128) {
        unsigned a1 = rk1[tid], a2 = rk2[tid];
        unsigned b1 = rk1[128 + tid], b2 = rk2[128 + tid];
        unsigned m1 = min(a1, b1);
        unsigned m2 = min(max(a1, b1), min(a2, b2));
        size_t o = ((size_t)b * 2 + half) * PPAD + pbase + tid;
        n1w[o] = (int)(m1 & 0xFFFu);
        n2w[o] = (int)(m2 & 0xFFFu);
    }
}

// ---------------- exact fp32 fixup over 4 candidates + all output writes ----------------
template<int MODE>
__global__ __launch_bounds__(256)
void fixup(const float* __restrict__ x, const float* __restrict__ xfT,
           const float* __restrict__ proto,
           const int* __restrict__ n1w, const int* __restrict__ n2w,
           float* __restrict__ out) {
    int tid = threadIdx.x;
    int lane = tid & 63, wv = tid >> 6;
    long long pair = (long long)blockIdx.x * 4 + wv;
    if (pair >= (long long)BATCH * PROT) return;
    int b = (int)(pair / PROT), p = (int)(pair % PROT);
    int cand[4];
    cand[0] = n1w[((size_t)b * 2 + 0) * PPAD + p];
    cand[1] = n2w[((size_t)b * 2 + 0) * PPAD + p];
    cand[2] = n1w[((size_t)b * 2 + 1) * PPAD + p];
    cand[3] = n2w[((size_t)b * 2 + 1) * PPAD + p];
    int d0 = lane, d1 = lane + 64;
    float pa0 = proto[(size_t)p * DDIM + d0], pa1 = proto[(size_t)p * DDIM + d1];
    float sp2 = pa0 * pa0 + pa1 * pa1;
    float f0[4], f1[4], sxp[4], sx2[4];
    #pragma unroll
    for (int c = 0; c < 4; ++c) {
        int n = cand[c];
        float a0, a1;
        if (MODE == 0) {
            const float* f = xfT + ((size_t)b * NPTS + n) * DDIM;
            a0 = f[d0]; a1 = f[d1];
        } else {
            const float* xb = x + (size_t)b * DDIM * NPTS;
            a0 = xb[(size_t)d0 * NPTS + n]; a1 = xb[(size_t)d1 * NPTS + n];
        }
        f0[c] = a0; f1[c] = a1;
        sxp[c] = a0 * pa0 + a1 * pa1;
        sx2[c] = a0 * a0 + a1 * a1;
    }
    #pragma unroll
    for (int m = 1; m < 64; m <<= 1) {
        sp2 += __shfl_xor(sp2, m, 64);
        #pragma unroll
        for (int c = 0; c < 4; ++c) {
            sxp[c] += __shfl_xor(sxp[c], m, 64);
            sx2[c] += __shfl_xor(sx2[c], m, 64);
        }
    }
    float d2c[4];
    #pragma unroll
    for (int c = 0; c < 4; ++c)
        d2c[c] = fmaxf(sx2[c] + sp2 - 2.f * sxp[c], 0.f);
    float bd = d2c[0]; int bn = cand[0]; float bf0 = f0[0], bf1 = f1[0];
    #pragma unroll
    for (int c = 1; c < 4; ++c) {
        bool w = (d2c[c] < bd) || (d2c[c] == bd && cand[c] < bn);
        bd  = w ? d2c[c] : bd;  bn  = w ? cand[c] : bn;
        bf0 = w ? f0[c] : bf0;  bf1 = w ? f1[c] : bf1;
    }
    float dm = sqrtf(bd);
    float sim = logf((dm + 1.0f) / (dm + 1e-7f));
    if (lane == 0) {
        out[(size_t)b * PROT + p] = sim;
        out[(size_t)BATCH * PROT + (size_t)b * PROT + p] = dm;
    }
    float* fo = out + (size_t)2 * BATCH * PROT + ((size_t)b * PROT + p) * DDIM;
    fo[d0] = bf0;
    fo[d1] = bf1;
}

// ================= fallback fp32 path (round-1, known-good) =================
#define TP 64
#define TN 64
__global__ void p2_kernel(const float* __restrict__ proto, float* __restrict__ p2) {
    int p = blockIdx.x * blockDim.x + threadIdx.x;
    if (p >= PROT) return;
    const float4* pr = reinterpret_cast<const float4*>(proto + (size_t)p * DDIM);
    float s = 0.f;
    #pragma unroll
    for (int i = 0; i < DDIM / 4; ++i) {
        float4 v = pr[i];
        s += v.x * v.x + v.y * v.y + v.z * v.z + v.w * v.w;
    }
    p2[p] = s;
}
__global__ void x2_kernel(const float* __restrict__ x, float* __restrict__ x2) {
    int idx = blockIdx.x * blockDim.x + threadIdx.x;
    if (idx >= BATCH * NPTS) return;
    int b = idx / NPTS, n = idx - b * NPTS;
    const float* xp = x + (size_t)b * DDIM * NPTS + n;
    float s = 0.f;
    #pragma unroll 8
    for (int d = 0; d < DDIM; ++d) { float v = xp[(size_t)d * NPTS]; s += v * v; }
    x2[idx] = s;
}
__global__ __launch_bounds__(256, 2)
void proto_main(const float* __restrict__ x, const float* __restrict__ proto,
                const float* __restrict__ p2, const float* __restrict__ x2,
                float* __restrict__ out) {
    __shared__ __align__(16) float xs[DDIM][TN];
    __shared__ __align__(16) float pst[DDIM][TP];
    __shared__ float p2s[TP];
    __shared__ float x2s[TN];
    __shared__ float red_d2[16][TP];
    __shared__ int   red_n[16][TP];
    __shared__ int   bestn_s[TP];
    const int b = blockIdx.y;
    const int pbase = blockIdx.x * TP;
    const int tid = threadIdx.x;
    {
        #pragma unroll
        for (int it = 0; it < (TP * DDIM / 4) / 256; ++it) {
            int idx = it * 256 + tid;
            int p = idx / (DDIM / 4);
            int dq = idx - p * (DDIM / 4);
            int gp = min(pbase + p, PROT - 1);
            float4 v = reinterpret_cast<const float4*>(proto)[(size_t)gp * (DDIM / 4) + dq];
            pst[dq * 4 + 0][p] = v.x; pst[dq * 4 + 1][p] = v.y;
            pst[dq * 4 + 2][p] = v.z; pst[dq * 4 + 3][p] = v.w;
        }
        if (tid < TP) p2s[tid] = p2[min(pbase + tid, PROT - 1)];
    }
    const int tn = tid >> 4;
    const int tp = tid & 15;
    float best[4]; int bestn[4];
    #pragma unroll
    for (int j = 0; j < 4; ++j) { best[j] = 1e30f; bestn[j] = 0; }
    for (int n0 = 0; n0 < NPTS; n0 += TN) {
        __syncthreads();
        {
            int r = tid >> 4, c = tid & 15;
            #pragma unroll
            for (int it = 0; it < 8; ++it) {
                int row = it * 16 + r;
                float4 v = *reinterpret_cast<const float4*>(
                    x + ((size_t)(b * DDIM + row)) * NPTS + n0 + c * 4);
                *reinterpret_cast<float4*>(&xs[row][c * 4]) = v;
            }
        }
        if (tid < TN) x2s[tid] = x2[b * NPTS + n0 + tid];
        __syncthreads();
        float acc[4][4];
        #pragma unroll
        for (int i = 0; i < 4; ++i)
            #pragma unroll
            for (int j = 0; j < 4; ++j) acc[i][j] = 0.f;
        #pragma unroll 16
        for (int d = 0; d < DDIM; ++d) {
            const float4 a = *reinterpret_cast<const float4*>(&xs[d][tn * 4]);
            const float4 bv = *reinterpret_cast<const float4*>(&pst[d][tp * 4]);
            const float av[4] = {a.x, a.y, a.z, a.w};
            const float bw[4] = {bv.x, bv.y, bv.z, bv.w};
            #pragma unroll
            for (int i = 0; i < 4; ++i)
                #pragma unroll
                for (int j = 0; j < 4; ++j) acc[i][j] = fmaf(av[i], bw[j], acc[i][j]);
        }
        #pragma unroll
        for (int i = 0; i < 4; ++i) {
            float xv = x2s[tn * 4 + i];
            int n = n0 + tn * 4 + i;
            #pragma unroll
            for (int j = 0; j < 4; ++j) {
                float d2 = xv + p2s[tp * 4 + j] - 2.0f * acc[i][j];
                if (d2 < best[j]) { best[j] = d2; bestn[j] = n; }
            }
        }
    }
    #pragma unroll
    for (int j = 0; j < 4; ++j) {
        red_d2[tn][tp * 4 + j] = best[j];
        red_n[tn][tp * 4 + j] = bestn[j];
    }
    __syncthreads();
    if (tid < TP) {
        float bd = red_d2[0][tid]; int bn = red_n[0][tid];
        #pragma unroll
        for (int t = 1; t < 16; ++t) {
            float dv = red_d2[t][tid]; int nv = red_n[t][tid];
            if (dv < bd || (dv == bd && nv < bn)) { bd = dv; bn = nv; }
        }
        int gp = pbase + tid;
        if (gp < PROT) {
            float d2c = fmaxf(bd, 0.f);
            float dmin = sqrtf(d2c);
            float sim = logf((dmin + 1.0f) / (dmin + 1e-7f));
            out[(size_t)b * PROT + gp] = sim;
            out[(size_t)BATCH * PROT + (size_t)b * PROT + gp] = dmin;
        }
        bestn_s[tid] = bn;
    }
    __syncthreads();
    {
        int pl = tid >> 2, dbase = (tid & 3) * 32;
        int gp = pbase + pl;
        if (gp < PROT) {
            int n = bestn_s[pl];
            float* dst = out + (size_t)2 * BATCH * PROT + ((size_t)(b * PROT + gp)) * DDIM + dbase;
            const float* src = x + ((size_t)(b * DDIM + dbase)) * NPTS + n;
            #pragma unroll 8
            for (int d = 0; d < 32; ++d) dst[d] = src[(size_t)d * NPTS];
        }
    }
}

extern "C" void kernel_launch(void* const* d_in, const int* in_sizes, int n_in,
                              void* d_out, int out_size, void* d_ws, size_t ws_size,
                              hipStream_t stream) {
    const float* x = (const float*)d_in[0];       // [16,128,56,56]
    const float* proto = (const float*)d_in[1];   // [1,2000,128]
    float* out = (float*)d_out;
    float* ws = (float*)d_ws;

    if (ws_size >= WS_MID) {
        bool big = (ws_size >= WS_BIG);
        float* x2 = ws + WS_X2;
        int* n1w = (int*)(ws + WS_N1);
        int* n2w = (int*)(ws + WS_N2);
        float* p2w = ws + WS_P2;
        unsigned short* pt = (unsigned short*)(ws + WS_PT);
        unsigned short* xt = (unsigned short*)(ws + WS_XT);
        float* xfT = big ? (ws + WS_XFT) : nullptr;

        pp_p<<<PPAD / 256, 256, 0, stream>>>(proto, pt, p2w);
        pp_x<<<dim3(NPTS / 64, BATCH), 256, 0, stream>>>(x, xt, x2, xfT);
        proto_mfma<<<512, 512, 0, stream>>>(xt, pt, x2, p2w, n1w, n2w);
        if (big)
            fixup<0><<<(BATCH * PROT) / 4, 256, 0, stream>>>(x, xfT, proto, n1w, n2w, out);
        else
            fixup<1><<<(BATCH * PROT) / 4, 256, 0, stream>>>(x, nullptr, proto, n1w, n2w, out);
    } else {
        float* p2 = ws;
        float* x2 = ws + 2048;
        p2_kernel<<<(PROT + 255) / 256, 256, 0, stream>>>(proto, p2);
        x2_kernel<<<(BATCH * NPTS + 255) / 256, 256, 0, stream>>>(x, x2);
        dim3 grid((PROT + TP - 1) / TP, BATCH);
        proto_main<<<grid, 256, 0, stream>>>(x, proto, p2, x2, out);
    }
}